// Round 1
// baseline (507.281 us; speedup 1.0000x reference)
//
#include <hip/hip_runtime.h>

#define NN 50000
#define EE 800000
#define ETOT (EE + NN)

// ---------------- GEMM: x_l = x@Wl + bl ; x_r = x@Wr + br ----------------
// block 256 threads, tile = 32 nodes x (128 L-cols + 128 R-cols), K=128
// thread (tx,ty): 4 nodes (ty*4..+3) x 4 cols (tx*4..+3) for BOTH matrices
__global__ __launch_bounds__(256) void gemm_xlxr(
    const float* __restrict__ x,
    const float* __restrict__ Wl, const float* __restrict__ bl,
    const float* __restrict__ Wr, const float* __restrict__ br,
    float* __restrict__ xl, float* __restrict__ xr) {
  __shared__ float xs[32][132];   // 32 nodes x full K=128 (pad to 132 floats)
  __shared__ float wt[16][264];   // 16 k-rows x (128 L | 128 R) (pad to 264)
  const int t = threadIdx.x;
  const int tx = t & 31, ty = t >> 5;
  const int bnode = blockIdx.x * 32;

#pragma unroll
  for (int i = 0; i < 4; ++i) {
    int idx = t + i * 256;
    int node = idx >> 5, f4 = idx & 31;
    int gn = bnode + node;
    float4 v = make_float4(0.f, 0.f, 0.f, 0.f);
    if (gn < NN) v = *(const float4*)&x[(size_t)gn * 128 + f4 * 4];
    *(float4*)&xs[node][f4 * 4] = v;
  }
  __syncthreads();

  float acc[2][4][4];
#pragma unroll
  for (int m = 0; m < 2; ++m)
#pragma unroll
    for (int n = 0; n < 4; ++n)
#pragma unroll
      for (int j = 0; j < 4; ++j) acc[m][n][j] = 0.f;

  for (int kt = 0; kt < 8; ++kt) {
    if (kt) __syncthreads();
#pragma unroll
    for (int i = 0; i < 4; ++i) {
      int idx = t + i * 256;
      int kk = idx >> 6, g = idx & 63;
      int krow = kt * 16 + kk;
      const float* s = (g < 32) ? &Wl[krow * 128 + g * 4]
                                : &Wr[krow * 128 + (g - 32) * 4];
      *(float4*)&wt[kk][g * 4] = *(const float4*)s;
    }
    __syncthreads();
#pragma unroll
    for (int kk4 = 0; kk4 < 4; ++kk4) {
      float xa[4][4];
#pragma unroll
      for (int n = 0; n < 4; ++n)
        *(float4*)&xa[n][0] = *(const float4*)&xs[ty * 4 + n][kt * 16 + kk4 * 4];
#pragma unroll
      for (int q = 0; q < 4; ++q) {
        float4 wl4 = *(const float4*)&wt[kk4 * 4 + q][tx * 4];
        float4 wr4 = *(const float4*)&wt[kk4 * 4 + q][128 + tx * 4];
        float wl_[4] = {wl4.x, wl4.y, wl4.z, wl4.w};
        float wr_[4] = {wr4.x, wr4.y, wr4.z, wr4.w};
#pragma unroll
        for (int n = 0; n < 4; ++n) {
          float xv = xa[n][q];
#pragma unroll
          for (int j = 0; j < 4; ++j) {
            acc[0][n][j] = fmaf(xv, wl_[j], acc[0][n][j]);
            acc[1][n][j] = fmaf(xv, wr_[j], acc[1][n][j]);
          }
        }
      }
    }
  }

  float4 bl4 = *(const float4*)&bl[tx * 4];
  float4 br4 = *(const float4*)&br[tx * 4];
#pragma unroll
  for (int n = 0; n < 4; ++n) {
    int gn = bnode + ty * 4 + n;
    if (gn < NN) {
      float4 o;
      o.x = acc[0][n][0] + bl4.x; o.y = acc[0][n][1] + bl4.y;
      o.z = acc[0][n][2] + bl4.z; o.w = acc[0][n][3] + bl4.w;
      *(float4*)&xl[(size_t)gn * 128 + tx * 4] = o;
      o.x = acc[1][n][0] + br4.x; o.y = acc[1][n][1] + br4.y;
      o.z = acc[1][n][2] + br4.z; o.w = acc[1][n][3] + br4.w;
      *(float4*)&xr[(size_t)gn * 128 + tx * 4] = o;
    }
  }
}

// ---------------- CSR build (segments = dst, incl. self loops) ----------------
__global__ void init_deg(int* __restrict__ deg) {
  int i = blockIdx.x * 256 + threadIdx.x;
  if (i < NN) deg[i] = 1;  // self loop
}

__global__ void count_deg(const int* __restrict__ ei, int* __restrict__ deg) {
  int e = blockIdx.x * 256 + threadIdx.x;
  if (e < EE) atomicAdd(&deg[ei[EE + e]], 1);
}

__global__ __launch_bounds__(1024) void scan_deg(const int* __restrict__ deg,
                                                 int* __restrict__ offs,
                                                 int* __restrict__ cursor) {
  __shared__ int part[1024];
  const int CHK = (NN + 1023) / 1024;  // 49
  int t = threadIdx.x;
  int base = t * CHK;
  int s = 0;
  for (int i = 0; i < CHK; ++i) {
    int idx = base + i;
    if (idx < NN) s += deg[idx];
  }
  part[t] = s;
  __syncthreads();
  for (int off = 1; off < 1024; off <<= 1) {
    int v = (t >= off) ? part[t - off] : 0;
    __syncthreads();
    part[t] += v;
    __syncthreads();
  }
  int run = (t == 0) ? 0 : part[t - 1];
  for (int i = 0; i < CHK; ++i) {
    int idx = base + i;
    if (idx < NN) {
      offs[idx] = run;
      cursor[idx] = run;
      run += deg[idx];
    }
  }
  if (t == 1023) offs[NN] = ETOT;
}

__global__ void fill_csr(const int* __restrict__ ei, int* __restrict__ cursor,
                         int* __restrict__ csr) {
  int e = blockIdx.x * 256 + threadIdx.x;
  if (e >= ETOT) return;
  int s, d;
  if (e < EE) { s = ei[e]; d = ei[EE + e]; }
  else { s = e - EE; d = s; }
  int pos = atomicAdd(&cursor[d], 1);
  csr[pos] = s;
}

// ---------------- fused score + online segment-softmax + aggregation ----------------
// 32-lane half-wave per dst node; lane covers 4 channels (float4).
// Head reduce = shfl_xor over 8-lane groups (8 lanes x 4 ch = 32 = HEAD_DIM).
__global__ __launch_bounds__(256) void aggregate(
    const float* __restrict__ xl, const float* __restrict__ xr,
    const int* __restrict__ offs, const int* __restrict__ csr,
    const float* __restrict__ att, const float* __restrict__ bias,
    float* __restrict__ out, float* __restrict__ bn) {
  __shared__ float sbn[256];
  sbn[threadIdx.x] = 0.f;
  __syncthreads();
  const int lane = threadIdx.x & 63;
  const int l32 = lane & 31;
  const int c4 = l32 * 4;
  const int slot = ((blockIdx.x * 4) + (threadIdx.x >> 6)) * 2 + (lane >> 5);
  const float4 attv = *(const float4*)&att[c4];
  const float4 bias4 = *(const float4*)&bias[c4];
  float4 bs = make_float4(0, 0, 0, 0), bq = make_float4(0, 0, 0, 0);

  for (int node = slot; node < NN; node += gridDim.x * 8) {
    const float4 xrv = *(const float4*)&xr[(size_t)node * 128 + c4];
    int beg = offs[node], end = offs[node + 1];
    float m = -1e30f, den = 0.f;
    float4 acc = make_float4(0, 0, 0, 0);
    for (int j = beg; j < end; ++j) {
      int src = csr[j];
      const float4 xlv = *(const float4*)&xl[(size_t)src * 128 + c4];
      float v, p;
      v = xlv.x + xrv.x; v = v > 0.f ? v : 0.2f * v; p = v * attv.x;
      v = xlv.y + xrv.y; v = v > 0.f ? v : 0.2f * v; p = fmaf(v, attv.y, p);
      v = xlv.z + xrv.z; v = v > 0.f ? v : 0.2f * v; p = fmaf(v, attv.z, p);
      v = xlv.w + xrv.w; v = v > 0.f ? v : 0.2f * v; p = fmaf(v, attv.w, p);
      p += __shfl_xor(p, 1);
      p += __shfl_xor(p, 2);
      p += __shfl_xor(p, 4);
      float mn = fmaxf(m, p);
      float sc = __expf(m - mn);
      float pe = __expf(p - mn);
      den = den * sc + pe;
      acc.x = fmaf(acc.x, sc, pe * xlv.x);
      acc.y = fmaf(acc.y, sc, pe * xlv.y);
      acc.z = fmaf(acc.z, sc, pe * xlv.z);
      acc.w = fmaf(acc.w, sc, pe * xlv.w);
      m = mn;
    }
    float inv = 1.0f / den;
    float4 r;
    r.x = acc.x * inv + bias4.x;
    r.y = acc.y * inv + bias4.y;
    r.z = acc.z * inv + bias4.z;
    r.w = acc.w * inv + bias4.w;
    *(float4*)&out[(size_t)node * 128 + c4] = r;
    bs.x += r.x; bs.y += r.y; bs.z += r.z; bs.w += r.w;
    bq.x += r.x * r.x; bq.y += r.y * r.y; bq.z += r.z * r.z; bq.w += r.w * r.w;
  }

  atomicAdd(&sbn[c4 + 0], bs.x);
  atomicAdd(&sbn[c4 + 1], bs.y);
  atomicAdd(&sbn[c4 + 2], bs.z);
  atomicAdd(&sbn[c4 + 3], bs.w);
  atomicAdd(&sbn[128 + c4 + 0], bq.x);
  atomicAdd(&sbn[128 + c4 + 1], bq.y);
  atomicAdd(&sbn[128 + c4 + 2], bq.z);
  atomicAdd(&sbn[128 + c4 + 3], bq.w);
  __syncthreads();
  atomicAdd(&bn[threadIdx.x], sbn[threadIdx.x]);
}

// ---------------- BN stats -> mu / inv_std ----------------
__global__ void bn_finalize(float* __restrict__ bn) {
  int c = threadIdx.x;  // 128
  float mu = bn[c] * (1.0f / NN);
  float var = bn[128 + c] * (1.0f / NN) - mu * mu;
  bn[256 + c] = mu;
  bn[384 + c] = rsqrtf(var + 1e-5f);
}

// ---------------- BN-normalize + residual + ELU (in place on d_out) ----------------
__global__ __launch_bounds__(256) void finalize(
    float* __restrict__ out, const float* __restrict__ x,
    const float* __restrict__ bn, const float* __restrict__ gamma,
    const float* __restrict__ beta) {
  const int total4 = NN * 32;
  for (int i = blockIdx.x * blockDim.x + threadIdx.x; i < total4;
       i += gridDim.x * blockDim.x) {
    int c4 = (i & 31) * 4;
    float4 o = ((const float4*)out)[i];
    float4 xv = ((const float4*)x)[i];
    float4 mu = *(const float4*)&bn[256 + c4];
    float4 is = *(const float4*)&bn[384 + c4];
    float4 g4 = *(const float4*)&gamma[c4];
    float4 b4 = *(const float4*)&beta[c4];
    float v;
    v = (o.x - mu.x) * is.x * g4.x + b4.x + xv.x; o.x = v > 0.f ? v : expm1f(v);
    v = (o.y - mu.y) * is.y * g4.y + b4.y + xv.y; o.y = v > 0.f ? v : expm1f(v);
    v = (o.z - mu.z) * is.z * g4.z + b4.z + xv.z; o.z = v > 0.f ? v : expm1f(v);
    v = (o.w - mu.w) * is.w * g4.w + b4.w + xv.w; o.w = v > 0.f ? v : expm1f(v);
    ((float4*)out)[i] = o;
  }
}

extern "C" void kernel_launch(void* const* d_in, const int* in_sizes, int n_in,
                              void* d_out, int out_size, void* d_ws, size_t ws_size,
                              hipStream_t stream) {
  const float* x    = (const float*)d_in[0];
  const int*   ei   = (const int*)d_in[1];
  const float* Wl   = (const float*)d_in[2];
  const float* bl   = (const float*)d_in[3];
  const float* Wr   = (const float*)d_in[4];
  const float* br   = (const float*)d_in[5];
  const float* att  = (const float*)d_in[6];
  const float* bias = (const float*)d_in[7];
  const float* gam  = (const float*)d_in[8];
  const float* bet  = (const float*)d_in[9];
  float* out = (float*)d_out;

  // workspace layout (all 16B-aligned)
  float* xl   = (float*)d_ws;                  // NN*128 f32
  float* xr   = xl + (size_t)NN * 128;         // NN*128 f32
  int* offs   = (int*)(xr + (size_t)NN * 128); // NN+4 ints (padded for alignment)
  int* cursor = offs + (NN + 4);               // NN ints
  int* deg    = cursor + NN;                   // NN ints
  int* csr    = deg + NN;                      // ETOT ints
  float* bn   = (float*)(csr + ETOT);          // 512 f32: sum|sumsq|mu|istd

  hipMemsetAsync(bn, 0, 256 * sizeof(float), stream);

  hipLaunchKernelGGL(gemm_xlxr, dim3((NN + 31) / 32), dim3(256), 0, stream,
                     x, Wl, bl, Wr, br, xl, xr);
  hipLaunchKernelGGL(init_deg, dim3((NN + 255) / 256), dim3(256), 0, stream, deg);
  hipLaunchKernelGGL(count_deg, dim3((EE + 255) / 256), dim3(256), 0, stream, ei, deg);
  hipLaunchKernelGGL(scan_deg, dim3(1), dim3(1024), 0, stream, deg, offs, cursor);
  hipLaunchKernelGGL(fill_csr, dim3((ETOT + 255) / 256), dim3(256), 0, stream,
                     ei, cursor, csr);
  hipLaunchKernelGGL(aggregate, dim3(1024), dim3(256), 0, stream,
                     xl, xr, offs, csr, att, bias, out, bn);
  hipLaunchKernelGGL(bn_finalize, dim3(1), dim3(128), 0, stream, bn);
  hipLaunchKernelGGL(finalize, dim3(2048), dim3(256), 0, stream, out, x, bn, gam, bet);
}

// Round 3
// 375.253 us; speedup vs baseline: 1.3518x; 1.3518x over previous
//
#include <hip/hip_runtime.h>

#define NN 50000
#define EE 800000
#define ETOT (EE + NN)

// ---------------- GEMM: x_l = x@Wl + bl ; x_r = x@Wr + br ----------------
__global__ __launch_bounds__(256) void gemm_xlxr(
    const float* __restrict__ x,
    const float* __restrict__ Wl, const float* __restrict__ bl,
    const float* __restrict__ Wr, const float* __restrict__ br,
    float* __restrict__ xl, float* __restrict__ xr) {
  __shared__ float xs[32][132];
  __shared__ float wt[16][264];
  const int t = threadIdx.x;
  const int tx = t & 31, ty = t >> 5;
  const int bnode = blockIdx.x * 32;

#pragma unroll
  for (int i = 0; i < 4; ++i) {
    int idx = t + i * 256;
    int node = idx >> 5, f4 = idx & 31;
    int gn = bnode + node;
    float4 v = make_float4(0.f, 0.f, 0.f, 0.f);
    if (gn < NN) v = *(const float4*)&x[(size_t)gn * 128 + f4 * 4];
    *(float4*)&xs[node][f4 * 4] = v;
  }
  __syncthreads();

  float acc[2][4][4];
#pragma unroll
  for (int m = 0; m < 2; ++m)
#pragma unroll
    for (int n = 0; n < 4; ++n)
#pragma unroll
      for (int j = 0; j < 4; ++j) acc[m][n][j] = 0.f;

  for (int kt = 0; kt < 8; ++kt) {
    if (kt) __syncthreads();
#pragma unroll
    for (int i = 0; i < 4; ++i) {
      int idx = t + i * 256;
      int kk = idx >> 6, g = idx & 63;
      int krow = kt * 16 + kk;
      const float* s = (g < 32) ? &Wl[krow * 128 + g * 4]
                                : &Wr[krow * 128 + (g - 32) * 4];
      *(float4*)&wt[kk][g * 4] = *(const float4*)s;
    }
    __syncthreads();
#pragma unroll
    for (int kk4 = 0; kk4 < 4; ++kk4) {
      float xa[4][4];
#pragma unroll
      for (int n = 0; n < 4; ++n)
        *(float4*)&xa[n][0] = *(const float4*)&xs[ty * 4 + n][kt * 16 + kk4 * 4];
#pragma unroll
      for (int q = 0; q < 4; ++q) {
        float4 wl4 = *(const float4*)&wt[kk4 * 4 + q][tx * 4];
        float4 wr4 = *(const float4*)&wt[kk4 * 4 + q][128 + tx * 4];
        float wl_[4] = {wl4.x, wl4.y, wl4.z, wl4.w};
        float wr_[4] = {wr4.x, wr4.y, wr4.z, wr4.w};
#pragma unroll
        for (int n = 0; n < 4; ++n) {
          float xv = xa[n][q];
#pragma unroll
          for (int j = 0; j < 4; ++j) {
            acc[0][n][j] = fmaf(xv, wl_[j], acc[0][n][j]);
            acc[1][n][j] = fmaf(xv, wr_[j], acc[1][n][j]);
          }
        }
      }
    }
  }

  float4 bl4 = *(const float4*)&bl[tx * 4];
  float4 br4 = *(const float4*)&br[tx * 4];
#pragma unroll
  for (int n = 0; n < 4; ++n) {
    int gn = bnode + ty * 4 + n;
    if (gn < NN) {
      float4 o;
      o.x = acc[0][n][0] + bl4.x; o.y = acc[0][n][1] + bl4.y;
      o.z = acc[0][n][2] + bl4.z; o.w = acc[0][n][3] + bl4.w;
      *(float4*)&xl[(size_t)gn * 128 + tx * 4] = o;
      o.x = acc[1][n][0] + br4.x; o.y = acc[1][n][1] + br4.y;
      o.z = acc[1][n][2] + br4.z; o.w = acc[1][n][3] + br4.w;
      *(float4*)&xr[(size_t)gn * 128 + tx * 4] = o;
    }
  }
}

// ---------------- CSR build ----------------
__global__ void count_deg(const int* __restrict__ ei, int* __restrict__ deg) {
  int e = blockIdx.x * 256 + threadIdx.x;
  if (e < EE) atomicAdd(&deg[ei[EE + e]], 1);
}

#define SCAN_BLOCKS 196  // ceil(50000/256)

__global__ __launch_bounds__(256) void scan1(const int* __restrict__ deg,
                                             int* __restrict__ bsum) {
  __shared__ int s[256];
  int t = threadIdx.x;
  int i = blockIdx.x * 256 + t;
  s[t] = (i < NN) ? deg[i] : 0;
  __syncthreads();
#pragma unroll
  for (int off = 128; off > 0; off >>= 1) {
    if (t < off) s[t] += s[t + off];
    __syncthreads();
  }
  if (t == 0) bsum[blockIdx.x] = s[0];
}

__global__ __launch_bounds__(256) void scan2(int* __restrict__ bsum) {
  __shared__ int s[256];
  int t = threadIdx.x;
  int orig = (t < SCAN_BLOCKS) ? bsum[t] : 0;
  s[t] = orig;
  __syncthreads();
  for (int off = 1; off < 256; off <<= 1) {
    int v = (t >= off) ? s[t - off] : 0;
    __syncthreads();
    s[t] += v;
    __syncthreads();
  }
  if (t < SCAN_BLOCKS) bsum[t] = s[t] - orig;  // exclusive
}

__global__ __launch_bounds__(256) void scan3(const int* __restrict__ deg,
                                             const int* __restrict__ bsum,
                                             int* __restrict__ offs,
                                             int* __restrict__ cursor) {
  __shared__ int s[256];
  int t = threadIdx.x;
  int i = blockIdx.x * 256 + t;
  int v = (i < NN) ? deg[i] : 0;
  s[t] = v;
  __syncthreads();
  for (int off = 1; off < 256; off <<= 1) {
    int u = (t >= off) ? s[t - off] : 0;
    __syncthreads();
    s[t] += u;
    __syncthreads();
  }
  int excl = s[t] - v + bsum[blockIdx.x];
  if (i <= NN) {
    offs[i] = excl;
    if (i < NN) cursor[i] = excl;
  }
}

__global__ void fill_csr(const int* __restrict__ ei, int* __restrict__ cursor,
                         int* __restrict__ csr) {
  int e = blockIdx.x * 256 + threadIdx.x;
  if (e >= ETOT) return;
  int s, d;
  if (e < EE) { s = ei[e]; d = ei[EE + e]; }
  else { s = e - EE; d = s; }
  int pos = atomicAdd(&cursor[d], 1);
  csr[pos] = s;
}

// ---------------- fused score + online segment-softmax + aggregation --------
// One 64-lane wave per dst node. lanes&31 = channel group (4 ch each);
// lane>>5 selects one of two edge streams; each half runs 2 independent
// online-softmax streams (4 edges in flight per wave step).
__device__ __forceinline__ float edge_score(const float4 xlv, const float4 xrv,
                                            const float4 attv) {
  float v, p;
  v = xlv.x + xrv.x; v = v > 0.f ? v : 0.2f * v; p = v * attv.x;
  v = xlv.y + xrv.y; v = v > 0.f ? v : 0.2f * v; p = fmaf(v, attv.y, p);
  v = xlv.z + xrv.z; v = v > 0.f ? v : 0.2f * v; p = fmaf(v, attv.z, p);
  v = xlv.w + xrv.w; v = v > 0.f ? v : 0.2f * v; p = fmaf(v, attv.w, p);
  p += __shfl_xor(p, 1);
  p += __shfl_xor(p, 2);
  p += __shfl_xor(p, 4);
  return p;
}

__global__ __launch_bounds__(256) void aggregate(
    const float* __restrict__ xl, const float* __restrict__ xr,
    const int* __restrict__ offs, const int* __restrict__ csr,
    const float* __restrict__ att, const float* __restrict__ bias,
    float* __restrict__ out, float* __restrict__ bn) {
  __shared__ float sbn[256];
  sbn[threadIdx.x] = 0.f;
  __syncthreads();
  const int lane = threadIdx.x & 63;
  const int l32 = lane & 31;
  const int half = lane >> 5;
  const int c4 = l32 * 4;
  const int wid = blockIdx.x * 4 + (threadIdx.x >> 6);
  const int wstride = gridDim.x * 4;
  const float4 attv = *(const float4*)&att[c4];
  const float4 bias4 = *(const float4*)&bias[c4];
  float4 bs = make_float4(0, 0, 0, 0), bq = make_float4(0, 0, 0, 0);

  for (int node = wid; node < NN; node += wstride) {
    const float4 xrv = *(const float4*)&xr[(size_t)node * 128 + c4];
    const int beg = offs[node];
    const int deg = offs[node + 1] - beg;
    float m0 = -1e30f, m1 = -1e30f, d0 = 0.f, d1 = 0.f;
    float4 a0 = make_float4(0, 0, 0, 0), a1 = make_float4(0, 0, 0, 0);

    for (int base = 0; base < deg; base += 64) {
      int cnt = deg - base; if (cnt > 64) cnt = 64;
      int msrc = (lane < cnt) ? csr[beg + base + lane] : 0;
      int nst = (cnt + 3) >> 2;
      for (int st = 0; st < nst; ++st) {
        int e0 = 4 * st + 2 * half;
        int e1 = e0 + 1;
        int s0 = __shfl(msrc, e0, 64);
        int s1 = __shfl(msrc, e1, 64);
        const float4 v0 = *(const float4*)&xl[(size_t)s0 * 128 + c4];
        const float4 v1 = *(const float4*)&xl[(size_t)s1 * 128 + c4];
        float p0 = edge_score(v0, xrv, attv);
        float p1 = edge_score(v1, xrv, attv);
        p0 = (e0 < cnt) ? p0 : -2e30f;
        p1 = (e1 < cnt) ? p1 : -2e30f;
        // stream 0
        {
          float mn = fmaxf(m0, p0);
          float sc = __expf(m0 - mn);
          float pe = __expf(p0 - mn);
          d0 = fmaf(d0, sc, pe);
          a0.x = fmaf(a0.x, sc, pe * v0.x);
          a0.y = fmaf(a0.y, sc, pe * v0.y);
          a0.z = fmaf(a0.z, sc, pe * v0.z);
          a0.w = fmaf(a0.w, sc, pe * v0.w);
          m0 = mn;
        }
        // stream 1
        {
          float mn = fmaxf(m1, p1);
          float sc = __expf(m1 - mn);
          float pe = __expf(p1 - mn);
          d1 = fmaf(d1, sc, pe);
          a1.x = fmaf(a1.x, sc, pe * v1.x);
          a1.y = fmaf(a1.y, sc, pe * v1.y);
          a1.z = fmaf(a1.z, sc, pe * v1.z);
          a1.w = fmaf(a1.w, sc, pe * v1.w);
          m1 = mn;
        }
      }
    }

    // merge stream1 into stream0 (in-half)
    float M = fmaxf(m0, m1);
    float w0 = __expf(m0 - M), w1 = __expf(m1 - M);
    float den = d0 * w0 + d1 * w1;
    float4 acc;
    acc.x = a0.x * w0 + a1.x * w1;
    acc.y = a0.y * w0 + a1.y * w1;
    acc.z = a0.z * w0 + a1.z * w1;
    acc.w = a0.w * w0 + a1.w * w1;
    // cross-half merge
    float Mo = __shfl_xor(M, 32);
    float deno = __shfl_xor(den, 32);
    float4 ao;
    ao.x = __shfl_xor(acc.x, 32);
    ao.y = __shfl_xor(acc.y, 32);
    ao.z = __shfl_xor(acc.z, 32);
    ao.w = __shfl_xor(acc.w, 32);
    float M2 = fmaxf(M, Mo);
    float u0 = __expf(M - M2), u1 = __expf(Mo - M2);
    den = den * u0 + deno * u1;
    acc.x = acc.x * u0 + ao.x * u1;
    acc.y = acc.y * u0 + ao.y * u1;
    acc.z = acc.z * u0 + ao.z * u1;
    acc.w = acc.w * u0 + ao.w * u1;

    if (half == 0) {
      float inv = 1.0f / den;
      float4 r;
      r.x = acc.x * inv + bias4.x;
      r.y = acc.y * inv + bias4.y;
      r.z = acc.z * inv + bias4.z;
      r.w = acc.w * inv + bias4.w;
      *(float4*)&out[(size_t)node * 128 + c4] = r;
      bs.x += r.x; bs.y += r.y; bs.z += r.z; bs.w += r.w;
      bq.x += r.x * r.x; bq.y += r.y * r.y; bq.z += r.z * r.z; bq.w += r.w * r.w;
    }
  }

  if (half == 0) {
    atomicAdd(&sbn[c4 + 0], bs.x);
    atomicAdd(&sbn[c4 + 1], bs.y);
    atomicAdd(&sbn[c4 + 2], bs.z);
    atomicAdd(&sbn[c4 + 3], bs.w);
    atomicAdd(&sbn[128 + c4 + 0], bq.x);
    atomicAdd(&sbn[128 + c4 + 1], bq.y);
    atomicAdd(&sbn[128 + c4 + 2], bq.z);
    atomicAdd(&sbn[128 + c4 + 3], bq.w);
  }
  __syncthreads();
  atomicAdd(&bn[threadIdx.x], sbn[threadIdx.x]);
}

// ---------------- BN-normalize + residual + ELU (bn_finalize folded in) -----
__global__ __launch_bounds__(256) void finalize(
    float* __restrict__ out, const float* __restrict__ x,
    const float* __restrict__ bn, const float* __restrict__ gamma,
    const float* __restrict__ beta) {
  __shared__ float smu[128], sgi[128];
  int t = threadIdx.x;
  if (t < 128) {
    float mu = bn[t] * (1.0f / NN);
    float var = bn[128 + t] * (1.0f / NN) - mu * mu;
    smu[t] = mu;
    sgi[t] = rsqrtf(var + 1e-5f) * gamma[t];
  }
  __syncthreads();
  const int total4 = NN * 32;
  for (int i = blockIdx.x * blockDim.x + threadIdx.x; i < total4;
       i += gridDim.x * blockDim.x) {
    int c4 = (i & 31) * 4;
    float4 o = ((const float4*)out)[i];
    float4 xv = ((const float4*)x)[i];
    float4 mu = *(const float4*)&smu[c4];
    float4 gi = *(const float4*)&sgi[c4];
    float4 b4 = *(const float4*)&beta[c4];
    float v;
    v = (o.x - mu.x) * gi.x + b4.x + xv.x; o.x = v > 0.f ? v : expm1f(v);
    v = (o.y - mu.y) * gi.y + b4.y + xv.y; o.y = v > 0.f ? v : expm1f(v);
    v = (o.z - mu.z) * gi.z + b4.z + xv.z; o.z = v > 0.f ? v : expm1f(v);
    v = (o.w - mu.w) * gi.w + b4.w + xv.w; o.w = v > 0.f ? v : expm1f(v);
    ((float4*)out)[i] = o;
  }
}

extern "C" void kernel_launch(void* const* d_in, const int* in_sizes, int n_in,
                              void* d_out, int out_size, void* d_ws, size_t ws_size,
                              hipStream_t stream) {
  const float* x    = (const float*)d_in[0];
  const int*   ei   = (const int*)d_in[1];
  const float* Wl   = (const float*)d_in[2];
  const float* bl   = (const float*)d_in[3];
  const float* Wr   = (const float*)d_in[4];
  const float* br   = (const float*)d_in[5];
  const float* att  = (const float*)d_in[6];
  const float* bias = (const float*)d_in[7];
  const float* gam  = (const float*)d_in[8];
  const float* bet  = (const float*)d_in[9];
  float* out = (float*)d_out;

  float* xl   = (float*)d_ws;                  // NN*128 f32
  float* xr   = xl + (size_t)NN * 128;         // NN*128 f32
  int* offs   = (int*)(xr + (size_t)NN * 128); // NN+4 ints
  int* cursor = offs + (NN + 4);               // NN ints
  int* deg    = cursor + NN;                   // NN ints
  int* csr    = deg + NN;                      // ETOT ints
  float* bn   = (float*)(csr + ETOT);          // 256 f32: sum | sumsq
  int* bsum   = (int*)(bn + 256);              // 256 ints

  hipMemsetAsync(bn, 0, 256 * sizeof(float), stream);
  hipMemsetD32Async((hipDeviceptr_t)deg, 1, NN, stream);  // self-loop

  hipLaunchKernelGGL(gemm_xlxr, dim3((NN + 31) / 32), dim3(256), 0, stream,
                     x, Wl, bl, Wr, br, xl, xr);
  hipLaunchKernelGGL(count_deg, dim3((EE + 255) / 256), dim3(256), 0, stream, ei, deg);
  hipLaunchKernelGGL(scan1, dim3(SCAN_BLOCKS), dim3(256), 0, stream, deg, bsum);
  hipLaunchKernelGGL(scan2, dim3(1), dim3(256), 0, stream, bsum);
  hipLaunchKernelGGL(scan3, dim3(SCAN_BLOCKS), dim3(256), 0, stream,
                     deg, bsum, offs, cursor);
  hipLaunchKernelGGL(fill_csr, dim3((ETOT + 255) / 256), dim3(256), 0, stream,
                     ei, cursor, csr);
  hipLaunchKernelGGL(aggregate, dim3(2048), dim3(256), 0, stream,
                     xl, xr, offs, csr, att, bias, out, bn);
  hipLaunchKernelGGL(finalize, dim3(2048), dim3(256), 0, stream, out, x, bn, gam, bet);
}

// Round 4
// 369.486 us; speedup vs baseline: 1.3729x; 1.0156x over previous
//
#include <hip/hip_runtime.h>

#define NN 50000
#define EE 800000
#define ETOT (EE + NN)

__device__ __forceinline__ unsigned bf16r(float f) {  // RNE float->bf16 bits
  unsigned u = __float_as_uint(f);
  return (u + 0x7FFFu + ((u >> 16) & 1u)) >> 16;
}

// ---------------- GEMM: xlh = bf16(x@Wl + bl) ; xr = x@Wr + br ----------------
__global__ __launch_bounds__(256) void gemm_xlxr(
    const float* __restrict__ x,
    const float* __restrict__ Wl, const float* __restrict__ bl,
    const float* __restrict__ Wr, const float* __restrict__ br,
    unsigned short* __restrict__ xlh, float* __restrict__ xr) {
  __shared__ float xs[32][132];
  __shared__ float wt[16][264];
  const int t = threadIdx.x;
  const int tx = t & 31, ty = t >> 5;
  const int bnode = blockIdx.x * 32;

#pragma unroll
  for (int i = 0; i < 4; ++i) {
    int idx = t + i * 256;
    int node = idx >> 5, f4 = idx & 31;
    int gn = bnode + node;
    float4 v = make_float4(0.f, 0.f, 0.f, 0.f);
    if (gn < NN) v = *(const float4*)&x[(size_t)gn * 128 + f4 * 4];
    *(float4*)&xs[node][f4 * 4] = v;
  }
  __syncthreads();

  float acc[2][4][4];
#pragma unroll
  for (int m = 0; m < 2; ++m)
#pragma unroll
    for (int n = 0; n < 4; ++n)
#pragma unroll
      for (int j = 0; j < 4; ++j) acc[m][n][j] = 0.f;

  for (int kt = 0; kt < 8; ++kt) {
    if (kt) __syncthreads();
#pragma unroll
    for (int i = 0; i < 4; ++i) {
      int idx = t + i * 256;
      int kk = idx >> 6, g = idx & 63;
      int krow = kt * 16 + kk;
      const float* s = (g < 32) ? &Wl[krow * 128 + g * 4]
                                : &Wr[krow * 128 + (g - 32) * 4];
      *(float4*)&wt[kk][g * 4] = *(const float4*)s;
    }
    __syncthreads();
#pragma unroll
    for (int kk4 = 0; kk4 < 4; ++kk4) {
      float xa[4][4];
#pragma unroll
      for (int n = 0; n < 4; ++n)
        *(float4*)&xa[n][0] = *(const float4*)&xs[ty * 4 + n][kt * 16 + kk4 * 4];
#pragma unroll
      for (int q = 0; q < 4; ++q) {
        float4 wl4 = *(const float4*)&wt[kk4 * 4 + q][tx * 4];
        float4 wr4 = *(const float4*)&wt[kk4 * 4 + q][128 + tx * 4];
        float wl_[4] = {wl4.x, wl4.y, wl4.z, wl4.w};
        float wr_[4] = {wr4.x, wr4.y, wr4.z, wr4.w};
#pragma unroll
        for (int n = 0; n < 4; ++n) {
          float xv = xa[n][q];
#pragma unroll
          for (int j = 0; j < 4; ++j) {
            acc[0][n][j] = fmaf(xv, wl_[j], acc[0][n][j]);
            acc[1][n][j] = fmaf(xv, wr_[j], acc[1][n][j]);
          }
        }
      }
    }
  }

  float4 bl4 = *(const float4*)&bl[tx * 4];
  float4 br4 = *(const float4*)&br[tx * 4];
#pragma unroll
  for (int n = 0; n < 4; ++n) {
    int gn = bnode + ty * 4 + n;
    if (gn < NN) {
      float ox = acc[0][n][0] + bl4.x, oy = acc[0][n][1] + bl4.y;
      float oz = acc[0][n][2] + bl4.z, ow = acc[0][n][3] + bl4.w;
      uint2 hv;
      hv.x = bf16r(ox) | (bf16r(oy) << 16);
      hv.y = bf16r(oz) | (bf16r(ow) << 16);
      *(uint2*)(xlh + (size_t)gn * 128 + tx * 4) = hv;
      float4 o;
      o.x = acc[1][n][0] + br4.x; o.y = acc[1][n][1] + br4.y;
      o.z = acc[1][n][2] + br4.z; o.w = acc[1][n][3] + br4.w;
      *(float4*)&xr[(size_t)gn * 128 + tx * 4] = o;
    }
  }
}

// ---------------- CSR build ----------------
__global__ void count_deg(const int* __restrict__ ei, int* __restrict__ deg) {
  int e = blockIdx.x * 256 + threadIdx.x;
  if (e < EE) atomicAdd(&deg[ei[EE + e]], 1);
}

#define SCAN_BLOCKS 196  // ceil(50000/256)

__global__ __launch_bounds__(256) void scan1(const int* __restrict__ deg,
                                             int* __restrict__ bsum) {
  __shared__ int s[256];
  int t = threadIdx.x;
  int i = blockIdx.x * 256 + t;
  s[t] = (i < NN) ? deg[i] : 0;
  __syncthreads();
#pragma unroll
  for (int off = 128; off > 0; off >>= 1) {
    if (t < off) s[t] += s[t + off];
    __syncthreads();
  }
  if (t == 0) bsum[blockIdx.x] = s[0];
}

__global__ __launch_bounds__(256) void scan2(int* __restrict__ bsum,
                                             float* __restrict__ bn) {
  __shared__ int s[256];
  int t = threadIdx.x;
  bn[t] = 0.f;  // zero BN accumulators (fused memset)
  int orig = (t < SCAN_BLOCKS) ? bsum[t] : 0;
  s[t] = orig;
  __syncthreads();
  for (int off = 1; off < 256; off <<= 1) {
    int v = (t >= off) ? s[t - off] : 0;
    __syncthreads();
    s[t] += v;
    __syncthreads();
  }
  if (t < SCAN_BLOCKS) bsum[t] = s[t] - orig;  // exclusive
}

__global__ __launch_bounds__(256) void scan3(const int* __restrict__ deg,
                                             const int* __restrict__ bsum,
                                             int* __restrict__ offs,
                                             int* __restrict__ cursor) {
  __shared__ int s[256];
  int t = threadIdx.x;
  int i = blockIdx.x * 256 + t;
  int v = (i < NN) ? deg[i] : 0;
  s[t] = v;
  __syncthreads();
  for (int off = 1; off < 256; off <<= 1) {
    int u = (t >= off) ? s[t - off] : 0;
    __syncthreads();
    s[t] += u;
    __syncthreads();
  }
  int excl = s[t] - v + bsum[blockIdx.x];
  if (i <= NN) {
    offs[i] = excl;
    if (i < NN) cursor[i] = excl;
  }
}

__global__ void fill_csr(const int* __restrict__ ei, int* __restrict__ cursor,
                         int* __restrict__ csr) {
  int e = blockIdx.x * 256 + threadIdx.x;
  if (e >= ETOT) return;
  int s, d;
  if (e < EE) { s = ei[e]; d = ei[EE + e]; }
  else { s = e - EE; d = s; }
  int pos = atomicAdd(&cursor[d], 1);
  csr[pos] = s;
}

// ---------------- fused score + segment-softmax (max-free) + aggregation ----
// One 64-lane wave per dst node. lane&31 = channel group (4 ch); each half
// processes 4 edges per step -> 8 independent bf16-row gathers in flight.
// No max subtraction: scores are O(1) here, exp() is safe; removes the
// serial online-softmax rescale chain so gathers fully pipeline.
__device__ __forceinline__ float edge_score(const float4 xlv, const float4 xrv,
                                            const float4 attv) {
  float v, p;
  v = xlv.x + xrv.x; v = v > 0.f ? v : 0.2f * v; p = v * attv.x;
  v = xlv.y + xrv.y; v = v > 0.f ? v : 0.2f * v; p = fmaf(v, attv.y, p);
  v = xlv.z + xrv.z; v = v > 0.f ? v : 0.2f * v; p = fmaf(v, attv.z, p);
  v = xlv.w + xrv.w; v = v > 0.f ? v : 0.2f * v; p = fmaf(v, attv.w, p);
  p += __shfl_xor(p, 1);
  p += __shfl_xor(p, 2);
  p += __shfl_xor(p, 4);
  return p;
}

__device__ __forceinline__ float4 unpack_bf16x4(uint2 d) {
  float4 f;
  f.x = __uint_as_float(d.x << 16);
  f.y = __uint_as_float(d.x & 0xFFFF0000u);
  f.z = __uint_as_float(d.y << 16);
  f.w = __uint_as_float(d.y & 0xFFFF0000u);
  return f;
}

__global__ __launch_bounds__(256) void aggregate(
    const unsigned short* __restrict__ xlh, const float* __restrict__ xr,
    const int* __restrict__ offs, const int* __restrict__ csr,
    const float* __restrict__ att, const float* __restrict__ bias,
    float* __restrict__ out, float* __restrict__ bn) {
  __shared__ float sbn[256];
  sbn[threadIdx.x] = 0.f;
  __syncthreads();
  const int lane = threadIdx.x & 63;
  const int l32 = lane & 31;
  const int half = lane >> 5;
  const int c4 = l32 * 4;
  const int wid = blockIdx.x * 4 + (threadIdx.x >> 6);
  const int wstride = gridDim.x * 4;
  const float4 attv = *(const float4*)&att[c4];
  const float4 bias4 = *(const float4*)&bias[c4];
  float4 bs = make_float4(0, 0, 0, 0), bq = make_float4(0, 0, 0, 0);

  for (int node = wid; node < NN; node += wstride) {
    const float4 xrv = *(const float4*)&xr[(size_t)node * 128 + c4];
    const int beg = offs[node];
    const int deg = offs[node + 1] - beg;
    float den = 0.f;
    float4 acc = make_float4(0, 0, 0, 0);

    for (int base = 0; base < deg; base += 64) {
      int cnt = deg - base; if (cnt > 64) cnt = 64;
      int msrc = (lane < cnt) ? csr[beg + base + lane] : 0;
      int nst = (cnt + 7) >> 3;
      for (int st = 0; st < nst; ++st) {
        const int eb = st * 8 + half * 4;
        int s0 = __shfl(msrc, eb + 0, 64);
        int s1 = __shfl(msrc, eb + 1, 64);
        int s2 = __shfl(msrc, eb + 2, 64);
        int s3 = __shfl(msrc, eb + 3, 64);
        uint2 u0 = *(const uint2*)(xlh + (size_t)s0 * 128 + c4);
        uint2 u1 = *(const uint2*)(xlh + (size_t)s1 * 128 + c4);
        uint2 u2 = *(const uint2*)(xlh + (size_t)s2 * 128 + c4);
        uint2 u3 = *(const uint2*)(xlh + (size_t)s3 * 128 + c4);
        float4 v0 = unpack_bf16x4(u0);
        float4 v1 = unpack_bf16x4(u1);
        float4 v2 = unpack_bf16x4(u2);
        float4 v3 = unpack_bf16x4(u3);
        float p0 = edge_score(v0, xrv, attv);
        float p1 = edge_score(v1, xrv, attv);
        float p2 = edge_score(v2, xrv, attv);
        float p3 = edge_score(v3, xrv, attv);
        float pe0 = (eb + 0 < cnt) ? __expf(p0) : 0.f;
        float pe1 = (eb + 1 < cnt) ? __expf(p1) : 0.f;
        float pe2 = (eb + 2 < cnt) ? __expf(p2) : 0.f;
        float pe3 = (eb + 3 < cnt) ? __expf(p3) : 0.f;
        den += (pe0 + pe1) + (pe2 + pe3);
        acc.x = fmaf(pe0, v0.x, fmaf(pe1, v1.x, fmaf(pe2, v2.x, fmaf(pe3, v3.x, acc.x))));
        acc.y = fmaf(pe0, v0.y, fmaf(pe1, v1.y, fmaf(pe2, v2.y, fmaf(pe3, v3.y, acc.y))));
        acc.z = fmaf(pe0, v0.z, fmaf(pe1, v1.z, fmaf(pe2, v2.z, fmaf(pe3, v3.z, acc.z))));
        acc.w = fmaf(pe0, v0.w, fmaf(pe1, v1.w, fmaf(pe2, v2.w, fmaf(pe3, v3.w, acc.w))));
      }
    }

    // cross-half reduce (both halves end with full sums)
    den += __shfl_xor(den, 32);
    acc.x += __shfl_xor(acc.x, 32);
    acc.y += __shfl_xor(acc.y, 32);
    acc.z += __shfl_xor(acc.z, 32);
    acc.w += __shfl_xor(acc.w, 32);

    if (half == 0) {
      float inv = 1.0f / den;
      float4 r;
      r.x = acc.x * inv + bias4.x;
      r.y = acc.y * inv + bias4.y;
      r.z = acc.z * inv + bias4.z;
      r.w = acc.w * inv + bias4.w;
      *(float4*)&out[(size_t)node * 128 + c4] = r;
      bs.x += r.x; bs.y += r.y; bs.z += r.z; bs.w += r.w;
      bq.x += r.x * r.x; bq.y += r.y * r.y; bq.z += r.z * r.z; bq.w += r.w * r.w;
    }
  }

  if (half == 0) {
    atomicAdd(&sbn[c4 + 0], bs.x);
    atomicAdd(&sbn[c4 + 1], bs.y);
    atomicAdd(&sbn[c4 + 2], bs.z);
    atomicAdd(&sbn[c4 + 3], bs.w);
    atomicAdd(&sbn[128 + c4 + 0], bq.x);
    atomicAdd(&sbn[128 + c4 + 1], bq.y);
    atomicAdd(&sbn[128 + c4 + 2], bq.z);
    atomicAdd(&sbn[128 + c4 + 3], bq.w);
  }
  __syncthreads();
  atomicAdd(&bn[threadIdx.x], sbn[threadIdx.x]);
}

// ---------------- BN-normalize + residual + ELU (in place on d_out) ----------
__global__ __launch_bounds__(256) void finalize(
    float* __restrict__ out, const float* __restrict__ x,
    const float* __restrict__ bn, const float* __restrict__ gamma,
    const float* __restrict__ beta) {
  __shared__ float smu[128], sgi[128];
  int t = threadIdx.x;
  if (t < 128) {
    float mu = bn[t] * (1.0f / NN);
    float var = bn[128 + t] * (1.0f / NN) - mu * mu;
    smu[t] = mu;
    sgi[t] = rsqrtf(var + 1e-5f) * gamma[t];
  }
  __syncthreads();
  const int total4 = NN * 32;
  for (int i = blockIdx.x * blockDim.x + threadIdx.x; i < total4;
       i += gridDim.x * blockDim.x) {
    int c4 = (i & 31) * 4;
    float4 o = ((const float4*)out)[i];
    float4 xv = ((const float4*)x)[i];
    float4 mu = *(const float4*)&smu[c4];
    float4 gi = *(const float4*)&sgi[c4];
    float4 b4 = *(const float4*)&beta[c4];
    float v;
    v = (o.x - mu.x) * gi.x + b4.x + xv.x; o.x = v > 0.f ? v : expm1f(v);
    v = (o.y - mu.y) * gi.y + b4.y + xv.y; o.y = v > 0.f ? v : expm1f(v);
    v = (o.z - mu.z) * gi.z + b4.z + xv.z; o.z = v > 0.f ? v : expm1f(v);
    v = (o.w - mu.w) * gi.w + b4.w + xv.w; o.w = v > 0.f ? v : expm1f(v);
    ((float4*)out)[i] = o;
  }
}

extern "C" void kernel_launch(void* const* d_in, const int* in_sizes, int n_in,
                              void* d_out, int out_size, void* d_ws, size_t ws_size,
                              hipStream_t stream) {
  const float* x    = (const float*)d_in[0];
  const int*   ei   = (const int*)d_in[1];
  const float* Wl   = (const float*)d_in[2];
  const float* bl   = (const float*)d_in[3];
  const float* Wr   = (const float*)d_in[4];
  const float* br   = (const float*)d_in[5];
  const float* att  = (const float*)d_in[6];
  const float* bias = (const float*)d_in[7];
  const float* gam  = (const float*)d_in[8];
  const float* bet  = (const float*)d_in[9];
  float* out = (float*)d_out;

  unsigned short* xlh = (unsigned short*)d_ws;        // NN*128 bf16
  float* xr   = (float*)(xlh + (size_t)NN * 128);     // NN*128 f32
  int* offs   = (int*)(xr + (size_t)NN * 128);        // NN+4 ints
  int* cursor = offs + (NN + 4);                      // NN ints
  int* deg    = cursor + NN;                          // NN ints
  int* csr    = deg + NN;                             // ETOT ints
  float* bn   = (float*)(csr + ETOT);                 // 256 f32: sum | sumsq
  int* bsum   = (int*)(bn + 256);                     // 256 ints

  hipMemsetD32Async((hipDeviceptr_t)deg, 1, NN, stream);  // self-loop

  hipLaunchKernelGGL(gemm_xlxr, dim3((NN + 31) / 32), dim3(256), 0, stream,
                     x, Wl, bl, Wr, br, xlh, xr);
  hipLaunchKernelGGL(count_deg, dim3((EE + 255) / 256), dim3(256), 0, stream, ei, deg);
  hipLaunchKernelGGL(scan1, dim3(SCAN_BLOCKS), dim3(256), 0, stream, deg, bsum);
  hipLaunchKernelGGL(scan2, dim3(1), dim3(256), 0, stream, bsum, bn);
  hipLaunchKernelGGL(scan3, dim3(SCAN_BLOCKS), dim3(256), 0, stream,
                     deg, bsum, offs, cursor);
  hipLaunchKernelGGL(fill_csr, dim3((ETOT + 255) / 256), dim3(256), 0, stream,
                     ei, cursor, csr);
  hipLaunchKernelGGL(aggregate, dim3(2048), dim3(256), 0, stream,
                     xlh, xr, offs, csr, att, bias, out, bn);
  hipLaunchKernelGGL(finalize, dim3(2048), dim3(256), 0, stream, out, x, bn, gam, bet);
}

// Round 6
// 348.626 us; speedup vs baseline: 1.4551x; 1.0598x over previous
//
#include <hip/hip_runtime.h>

#define NN 50000
#define EE 800000
#define ETOT (EE + NN)
#define GEMM_BLOCKS 1563   // ceil(NN/32)
#define COUNT_BLOCKS 3125  // ceil(EE/256)
#define SCAN_BLOCKS 196    // ceil(NN/256)

__device__ __forceinline__ unsigned bf16r(float f) {  // RNE float->bf16 bits
  unsigned u = __float_as_uint(f);
  return (u + 0x7FFFu + ((u >> 16) & 1u)) >> 16;
}

__device__ __forceinline__ float4 unpack_bf16x4(unsigned a, unsigned b) {
  float4 f;
  f.x = __uint_as_float(a << 16);
  f.y = __uint_as_float(a & 0xFFFF0000u);
  f.z = __uint_as_float(b << 16);
  f.w = __uint_as_float(b & 0xFFFF0000u);
  return f;
}

// ------- fused: GEMM (blocks 0..1562)  |  degree count (blocks 1563..4687) --
__global__ __launch_bounds__(256) void gemm_count(
    const float* __restrict__ x,
    const float* __restrict__ Wl, const float* __restrict__ bl,
    const float* __restrict__ Wr, const float* __restrict__ br,
    unsigned short* __restrict__ xlh, float* __restrict__ xr,
    const int* __restrict__ ei, int* __restrict__ deg) {
  __shared__ float xs[32][132];
  __shared__ float wt[16][264];
  if (blockIdx.x >= GEMM_BLOCKS) {
    int e = (blockIdx.x - GEMM_BLOCKS) * 256 + threadIdx.x;
    if (e < EE) atomicAdd(&deg[ei[EE + e]], 1);
    return;
  }
  const int t = threadIdx.x;
  const int tx = t & 31, ty = t >> 5;
  const int bnode = blockIdx.x * 32;

#pragma unroll
  for (int i = 0; i < 4; ++i) {
    int idx = t + i * 256;
    int node = idx >> 5, f4 = idx & 31;
    int gn = bnode + node;
    float4 v = make_float4(0.f, 0.f, 0.f, 0.f);
    if (gn < NN) v = *(const float4*)&x[(size_t)gn * 128 + f4 * 4];
    *(float4*)&xs[node][f4 * 4] = v;
  }
  __syncthreads();

  float acc[2][4][4];
#pragma unroll
  for (int m = 0; m < 2; ++m)
#pragma unroll
    for (int n = 0; n < 4; ++n)
#pragma unroll
      for (int j = 0; j < 4; ++j) acc[m][n][j] = 0.f;

  for (int kt = 0; kt < 8; ++kt) {
    if (kt) __syncthreads();
#pragma unroll
    for (int i = 0; i < 4; ++i) {
      int idx = t + i * 256;
      int kk = idx >> 6, g = idx & 63;
      int krow = kt * 16 + kk;
      const float* s = (g < 32) ? &Wl[krow * 128 + g * 4]
                                : &Wr[krow * 128 + (g - 32) * 4];
      *(float4*)&wt[kk][g * 4] = *(const float4*)s;
    }
    __syncthreads();
#pragma unroll
    for (int kk4 = 0; kk4 < 4; ++kk4) {
      float xa[4][4];
#pragma unroll
      for (int n = 0; n < 4; ++n)
        *(float4*)&xa[n][0] = *(const float4*)&xs[ty * 4 + n][kt * 16 + kk4 * 4];
#pragma unroll
      for (int q = 0; q < 4; ++q) {
        float4 wl4 = *(const float4*)&wt[kk4 * 4 + q][tx * 4];
        float4 wr4 = *(const float4*)&wt[kk4 * 4 + q][128 + tx * 4];
        float wl_[4] = {wl4.x, wl4.y, wl4.z, wl4.w};
        float wr_[4] = {wr4.x, wr4.y, wr4.z, wr4.w};
#pragma unroll
        for (int n = 0; n < 4; ++n) {
          float xv = xa[n][q];
#pragma unroll
          for (int j = 0; j < 4; ++j) {
            acc[0][n][j] = fmaf(xv, wl_[j], acc[0][n][j]);
            acc[1][n][j] = fmaf(xv, wr_[j], acc[1][n][j]);
          }
        }
      }
    }
  }

  float4 bl4 = *(const float4*)&bl[tx * 4];
  float4 br4 = *(const float4*)&br[tx * 4];
#pragma unroll
  for (int n = 0; n < 4; ++n) {
    int gn = bnode + ty * 4 + n;
    if (gn < NN) {
      float ox = acc[0][n][0] + bl4.x, oy = acc[0][n][1] + bl4.y;
      float oz = acc[0][n][2] + bl4.z, ow = acc[0][n][3] + bl4.w;
      uint2 hv;
      hv.x = bf16r(ox) | (bf16r(oy) << 16);
      hv.y = bf16r(oz) | (bf16r(ow) << 16);
      *(uint2*)(xlh + (size_t)gn * 128 + tx * 4) = hv;
      float4 o;
      o.x = acc[1][n][0] + br4.x; o.y = acc[1][n][1] + br4.y;
      o.z = acc[1][n][2] + br4.z; o.w = acc[1][n][3] + br4.w;
      *(float4*)&xr[(size_t)gn * 128 + tx * 4] = o;
    }
  }
}

// ---------------- scanA: per-block reduce of deg; zero bn ----------------
__global__ __launch_bounds__(256) void scanA(const int* __restrict__ deg,
                                             int* __restrict__ bsum,
                                             float* __restrict__ bn) {
  __shared__ int s[256];
  int t = threadIdx.x;
  if (blockIdx.x == 0) bn[t] = 0.f;
  int i = blockIdx.x * 256 + t;
  s[t] = (i < NN) ? deg[i] : 0;
  __syncthreads();
#pragma unroll
  for (int off = 128; off > 0; off >>= 1) {
    if (t < off) s[t] += s[t + off];
    __syncthreads();
  }
  if (t == 0) bsum[blockIdx.x] = s[0];
}

// -------- scanB: redundant block-prefix + local scan -> offs / cursor -------
__global__ __launch_bounds__(256) void scanB(const int* __restrict__ deg,
                                             const int* __restrict__ bsum,
                                             int* __restrict__ offs,
                                             int* __restrict__ cursor) {
  __shared__ int s[256];
  __shared__ int bpref;
  int t = threadIdx.x;
  int bid = blockIdx.x;
  int i = bid * 256 + t;
  int v = (i < NN) ? deg[i] : 0;
  s[t] = v;
  if (t == 0) {
    int r = 0;
    for (int k = 0; k < bid; ++k) r += bsum[k];
    bpref = r;
  }
  __syncthreads();
  for (int off = 1; off < 256; off <<= 1) {
    int u = (t >= off) ? s[t - off] : 0;
    __syncthreads();
    s[t] += u;
    __syncthreads();
  }
  int excl = s[t] - v + bpref;
  if (i <= NN) {
    offs[i] = excl;
    if (i < NN) cursor[i] = excl;
  }
}

__global__ void fill_csr(const int* __restrict__ ei, int* __restrict__ cursor,
                         int* __restrict__ csr) {
  int e = blockIdx.x * 256 + threadIdx.x;
  if (e >= ETOT) return;
  int s, d;
  if (e < EE) { s = ei[e]; d = ei[EE + e]; }
  else { s = e - EE; d = s; }
  int pos = atomicAdd(&cursor[d], 1);
  csr[pos] = s;
}

// ---------------- fused score + segment-softmax (max-free) + aggregation ----
// One node per 16-lane group (8 ch/lane), 4 nodes per wave. Per sub-step each
// group issues 8 uint4 row-gathers -> 32 rows in flight per wave. Head score
// reduce = 2 shfl_xor within 4-lane quads. Post-agg bias dropped (cancels in BN).
__global__ __launch_bounds__(256) void aggregate(
    const unsigned short* __restrict__ xlh, const float* __restrict__ xr,
    const int* __restrict__ offs, const int* __restrict__ csr,
    const float* __restrict__ att,
    float* __restrict__ out, float* __restrict__ bn) {
  __shared__ float sbn[256];
  int t = threadIdx.x;
  sbn[t] = 0.f;
  __syncthreads();
  const int lane = t & 63;
  const int gl = lane & 15;          // lane within group
  const int gb = lane & 48;          // group base lane (grp*16)
  const int c8 = gl * 8;
  const int gid = (blockIdx.x * 256 + t) >> 4;
  const int gstride = gridDim.x * 16;
  const float4 at0 = *(const float4*)&att[c8];
  const float4 at1 = *(const float4*)&att[c8 + 4];
  float4 bs0 = make_float4(0, 0, 0, 0), bs1 = make_float4(0, 0, 0, 0);
  float4 bq0 = make_float4(0, 0, 0, 0), bq1 = make_float4(0, 0, 0, 0);

  for (int node = gid; node < NN; node += gstride) {
    const float4 xr0 = *(const float4*)&xr[(size_t)node * 128 + c8];
    const float4 xr1 = *(const float4*)&xr[(size_t)node * 128 + c8 + 4];
    const int beg = offs[node];
    const int deg = offs[node + 1] - beg;
    float den = 0.f;
    float4 a0 = make_float4(0, 0, 0, 0), a1 = make_float4(0, 0, 0, 0);

    for (int base = 0; base < deg; base += 16) {
      int cnt = deg - base; if (cnt > 16) cnt = 16;
      int msrc = (gl < cnt) ? csr[beg + base + gl] : 0;
      for (int eb = 0; eb < cnt; eb += 8) {
        uint4 u[8];
#pragma unroll
        for (int j = 0; j < 8; ++j) {
          int s = __shfl(msrc, gb + eb + j, 64);
          u[j] = *(const uint4*)(xlh + (size_t)s * 128 + c8);
        }
#pragma unroll
        for (int j = 0; j < 8; ++j) {
          float4 v0 = unpack_bf16x4(u[j].x, u[j].y);
          float4 v1 = unpack_bf16x4(u[j].z, u[j].w);
          float e, p;
          e = v0.x + xr0.x; e = e > 0.f ? e : 0.2f * e; p = e * at0.x;
          e = v0.y + xr0.y; e = e > 0.f ? e : 0.2f * e; p = fmaf(e, at0.y, p);
          e = v0.z + xr0.z; e = e > 0.f ? e : 0.2f * e; p = fmaf(e, at0.z, p);
          e = v0.w + xr0.w; e = e > 0.f ? e : 0.2f * e; p = fmaf(e, at0.w, p);
          e = v1.x + xr1.x; e = e > 0.f ? e : 0.2f * e; p = fmaf(e, at1.x, p);
          e = v1.y + xr1.y; e = e > 0.f ? e : 0.2f * e; p = fmaf(e, at1.y, p);
          e = v1.z + xr1.z; e = e > 0.f ? e : 0.2f * e; p = fmaf(e, at1.z, p);
          e = v1.w + xr1.w; e = e > 0.f ? e : 0.2f * e; p = fmaf(e, at1.w, p);
          p += __shfl_xor(p, 1);
          p += __shfl_xor(p, 2);
          float pe = (eb + j < cnt) ? __expf(p) : 0.f;
          den += pe;
          a0.x = fmaf(pe, v0.x, a0.x);
          a0.y = fmaf(pe, v0.y, a0.y);
          a0.z = fmaf(pe, v0.z, a0.z);
          a0.w = fmaf(pe, v0.w, a0.w);
          a1.x = fmaf(pe, v1.x, a1.x);
          a1.y = fmaf(pe, v1.y, a1.y);
          a1.z = fmaf(pe, v1.z, a1.z);
          a1.w = fmaf(pe, v1.w, a1.w);
        }
      }
    }

    float inv = 1.0f / den;
    float4 r0, r1;
    r0.x = a0.x * inv; r0.y = a0.y * inv; r0.z = a0.z * inv; r0.w = a0.w * inv;
    r1.x = a1.x * inv; r1.y = a1.y * inv; r1.z = a1.z * inv; r1.w = a1.w * inv;
    *(float4*)&out[(size_t)node * 128 + c8] = r0;
    *(float4*)&out[(size_t)node * 128 + c8 + 4] = r1;
    bs0.x += r0.x; bs0.y += r0.y; bs0.z += r0.z; bs0.w += r0.w;
    bs1.x += r1.x; bs1.y += r1.y; bs1.z += r1.z; bs1.w += r1.w;
    bq0.x += r0.x * r0.x; bq0.y += r0.y * r0.y; bq0.z += r0.z * r0.z; bq0.w += r0.w * r0.w;
    bq1.x += r1.x * r1.x; bq1.y += r1.y * r1.y; bq1.z += r1.z * r1.z; bq1.w += r1.w * r1.w;
  }

  // reduce across the 4 groups of the wave (lanes with equal gl)
#define RED(F) F = F + __shfl_xor(F, 16); F = F + __shfl_xor(F, 32);
  RED(bs0.x) RED(bs0.y) RED(bs0.z) RED(bs0.w)
  RED(bs1.x) RED(bs1.y) RED(bs1.z) RED(bs1.w)
  RED(bq0.x) RED(bq0.y) RED(bq0.z) RED(bq0.w)
  RED(bq1.x) RED(bq1.y) RED(bq1.z) RED(bq1.w)
#undef RED
  if (lane < 16) {
    atomicAdd(&sbn[c8 + 0], bs0.x);
    atomicAdd(&sbn[c8 + 1], bs0.y);
    atomicAdd(&sbn[c8 + 2], bs0.z);
    atomicAdd(&sbn[c8 + 3], bs0.w);
    atomicAdd(&sbn[c8 + 4], bs1.x);
    atomicAdd(&sbn[c8 + 5], bs1.y);
    atomicAdd(&sbn[c8 + 6], bs1.z);
    atomicAdd(&sbn[c8 + 7], bs1.w);
    atomicAdd(&sbn[128 + c8 + 0], bq0.x);
    atomicAdd(&sbn[128 + c8 + 1], bq0.y);
    atomicAdd(&sbn[128 + c8 + 2], bq0.z);
    atomicAdd(&sbn[128 + c8 + 3], bq0.w);
    atomicAdd(&sbn[128 + c8 + 4], bq1.x);
    atomicAdd(&sbn[128 + c8 + 5], bq1.y);
    atomicAdd(&sbn[128 + c8 + 6], bq1.z);
    atomicAdd(&sbn[128 + c8 + 7], bq1.w);
  }
  __syncthreads();
  atomicAdd(&bn[t], sbn[t]);
}

// ---------------- BN-normalize + residual + ELU (in place on d_out) ----------
__global__ __launch_bounds__(256) void finalize(
    float* __restrict__ out, const float* __restrict__ x,
    const float* __restrict__ bn, const float* __restrict__ gamma,
    const float* __restrict__ beta) {
  __shared__ float smu[128], sgi[128];
  int t = threadIdx.x;
  if (t < 128) {
    float mu = bn[t] * (1.0f / NN);
    float var = bn[128 + t] * (1.0f / NN) - mu * mu;
    smu[t] = mu;
    sgi[t] = rsqrtf(var + 1e-5f) * gamma[t];
  }
  __syncthreads();
  const int total4 = NN * 32;
  for (int i = blockIdx.x * blockDim.x + threadIdx.x; i < total4;
       i += gridDim.x * blockDim.x) {
    int c4 = (i & 31) * 4;
    float4 o = ((const float4*)out)[i];
    float4 xv = ((const float4*)x)[i];
    float4 mu = *(const float4*)&smu[c4];
    float4 gi = *(const float4*)&sgi[c4];
    float4 b4 = *(const float4*)&beta[c4];
    float v;
    v = (o.x - mu.x) * gi.x + b4.x + xv.x; o.x = v > 0.f ? v : expm1f(v);
    v = (o.y - mu.y) * gi.y + b4.y + xv.y; o.y = v > 0.f ? v : expm1f(v);
    v = (o.z - mu.z) * gi.z + b4.z + xv.z; o.z = v > 0.f ? v : expm1f(v);
    v = (o.w - mu.w) * gi.w + b4.w + xv.w; o.w = v > 0.f ? v : expm1f(v);
    ((float4*)out)[i] = o;
  }
}

extern "C" void kernel_launch(void* const* d_in, const int* in_sizes, int n_in,
                              void* d_out, int out_size, void* d_ws, size_t ws_size,
                              hipStream_t stream) {
  const float* x    = (const float*)d_in[0];
  const int*   ei   = (const int*)d_in[1];
  const float* Wl   = (const float*)d_in[2];
  const float* bl   = (const float*)d_in[3];
  const float* Wr   = (const float*)d_in[4];
  const float* br   = (const float*)d_in[5];
  const float* att  = (const float*)d_in[6];
  const float* gam  = (const float*)d_in[8];
  const float* bet  = (const float*)d_in[9];
  float* out = (float*)d_out;

  unsigned short* xlh = (unsigned short*)d_ws;        // NN*128 bf16
  float* xr   = (float*)(xlh + (size_t)NN * 128);     // NN*128 f32
  int* offs   = (int*)(xr + (size_t)NN * 128);        // NN+4 ints
  int* cursor = offs + (NN + 4);                      // NN ints
  int* deg    = cursor + NN;                          // NN ints
  int* csr    = deg + NN;                             // ETOT ints
  float* bn   = (float*)(csr + ETOT);                 // 256 f32: sum | sumsq
  int* bsum   = (int*)(bn + 256);                     // 256 ints

  hipMemsetD32Async((hipDeviceptr_t)deg, 1, NN, stream);  // self-loop

  hipLaunchKernelGGL(gemm_count, dim3(GEMM_BLOCKS + COUNT_BLOCKS), dim3(256), 0,
                     stream, x, Wl, bl, Wr, br, xlh, xr, ei, deg);
  hipLaunchKernelGGL(scanA, dim3(SCAN_BLOCKS), dim3(256), 0, stream, deg, bsum, bn);
  hipLaunchKernelGGL(scanB, dim3(SCAN_BLOCKS), dim3(256), 0, stream,
                     deg, bsum, offs, cursor);
  hipLaunchKernelGGL(fill_csr, dim3((ETOT + 255) / 256), dim3(256), 0, stream,
                     ei, cursor, csr);
  hipLaunchKernelGGL(aggregate, dim3(GEMM_BLOCKS), dim3(256), 0, stream,
                     xlh, xr, offs, csr, att, out, bn);
  hipLaunchKernelGGL(finalize, dim3(2048), dim3(256), 0, stream, out, x, bn, gam, bet);
}

// Round 7
// 298.814 us; speedup vs baseline: 1.6976x; 1.1667x over previous
//
#include <hip/hip_runtime.h>

#define NN 50000
#define EE 800000
#define ETOT (EE + NN)
#define GEMM_GRID 512      // persistent blocks for MFMA gemm
#define MTILES 782         // ceil(NN/64)
#define COUNT_BLOCKS 3125  // EE/256 exactly
#define AGG_BLOCKS 1563
#define SCAN_BLOCKS 196    // ceil(NN/256)

typedef __attribute__((ext_vector_type(8))) short bhalf8;  // 8 bf16 (4 VGPR)
typedef __attribute__((ext_vector_type(4))) float fx4;     // mfma acc

__device__ __forceinline__ unsigned bf16r(float f) {  // RNE float->bf16 bits
  unsigned u = __float_as_uint(f);
  return (u + 0x7FFFu + ((u >> 16) & 1u)) >> 16;
}

__device__ __forceinline__ float4 unpack_bf16x4(unsigned a, unsigned b) {
  float4 f;
  f.x = __uint_as_float(a << 16);
  f.y = __uint_as_float(a & 0xFFFF0000u);
  f.z = __uint_as_float(b << 16);
  f.w = __uint_as_float(b & 0xFFFF0000u);
  return f;
}

// ---- fused: MFMA GEMM (blocks 0..511) | degree count (blocks 512..3636) ----
// GEMM: [50000x128] @ [128x(128|128)] -> xlh (bf16), xr (f32), bias folded in.
// Per block: 4 waves; wave w owns output cols [w*64, w*64+64).
// W bf16 frags live in registers (64 VGPR/wave), loaded once per block.
// A-frag: row = lane&15, k = (lane>>4)*8+j ; B-frag: col = lane&15, same k.
// C/D: col = lane&15, row = (lane>>4)*4 + reg   [m89-verified layout]
__global__ __launch_bounds__(256) void gemm_count(
    const float* __restrict__ x,
    const float* __restrict__ Wl, const float* __restrict__ bl,
    const float* __restrict__ Wr, const float* __restrict__ br,
    unsigned short* __restrict__ xlh, float* __restrict__ xr,
    const int* __restrict__ ei, int* __restrict__ deg) {
  if (blockIdx.x >= GEMM_GRID) {
    int e = (blockIdx.x - GEMM_GRID) * 256 + threadIdx.x;
    if (e < EE) atomicAdd(&deg[ei[EE + e]], 1);
    return;
  }
  const int t = threadIdx.x;
  const int w = t >> 6;        // wave 0..3
  const int l = t & 63;
  const int cl = l & 15;       // row (A) / col (B,D) within 16
  const int kb = (l >> 4) * 8; // k sub-offset within 32-chunk
  const int rsub = (l >> 4) * 4;

  // ---- load W fragments (one-time) ----
  bhalf8 bfr[4][4];  // [nt][ch]
  float biasv[4];
#pragma unroll
  for (int nt = 0; nt < 4; ++nt) {
    int col = w * 64 + nt * 16 + cl;  // 0..255, wave-uniform side of 128-split
    const float* Wsrc;
    if (col < 128) { Wsrc = Wl + col; biasv[nt] = bl[col]; }
    else           { Wsrc = Wr + (col - 128); biasv[nt] = br[col - 128]; }
#pragma unroll
    for (int ch = 0; ch < 4; ++ch) {
      int k0 = ch * 32 + kb;
      bhalf8 f;
#pragma unroll
      for (int j = 0; j < 8; ++j)
        f[j] = (short)bf16r(Wsrc[(size_t)(k0 + j) * 128]);
      bfr[nt][ch] = f;
    }
  }

  // ---- persistent M-tile loop (64 rows per tile) ----
  for (int mt = blockIdx.x; mt < MTILES; mt += GEMM_GRID) {
    const int m0 = mt * 64;
#pragma unroll
    for (int rt = 0; rt < 4; ++rt) {
      int row = m0 + rt * 16 + cl;
      int rowc = row < NN ? row : NN - 1;
      const float* xp = x + (size_t)rowc * 128 + kb;
      bhalf8 afr[4];
#pragma unroll
      for (int ch = 0; ch < 4; ++ch) {
        float4 q0 = *(const float4*)(xp + ch * 32);
        float4 q1 = *(const float4*)(xp + ch * 32 + 4);
        bhalf8 f;
        f[0] = (short)bf16r(q0.x); f[1] = (short)bf16r(q0.y);
        f[2] = (short)bf16r(q0.z); f[3] = (short)bf16r(q0.w);
        f[4] = (short)bf16r(q1.x); f[5] = (short)bf16r(q1.y);
        f[6] = (short)bf16r(q1.z); f[7] = (short)bf16r(q1.w);
        afr[ch] = f;
      }
#pragma unroll
      for (int nt = 0; nt < 4; ++nt) {
        fx4 acc = {biasv[nt], biasv[nt], biasv[nt], biasv[nt]};
#pragma unroll
        for (int ch = 0; ch < 4; ++ch)
          acc = __builtin_amdgcn_mfma_f32_16x16x32_bf16(afr[ch], bfr[nt][ch],
                                                        acc, 0, 0, 0);
        int col = w * 64 + nt * 16 + cl;
        int rbase = m0 + rt * 16 + rsub;
        if (col < 128) {  // wave-uniform branch
#pragma unroll
          for (int r = 0; r < 4; ++r) {
            int rr = rbase + r;
            if (rr < NN) xlh[(size_t)rr * 128 + col] = (unsigned short)bf16r(acc[r]);
          }
        } else {
          int c2 = col - 128;
#pragma unroll
          for (int r = 0; r < 4; ++r) {
            int rr = rbase + r;
            if (rr < NN) xr[(size_t)rr * 128 + c2] = acc[r];
          }
        }
      }
    }
  }
}

// ---------------- scanA: per-block reduce of deg; zero bn ----------------
__global__ __launch_bounds__(256) void scanA(const int* __restrict__ deg,
                                             int* __restrict__ bsum,
                                             float* __restrict__ bn) {
  __shared__ int s[256];
  int t = threadIdx.x;
  if (blockIdx.x == 0) bn[t] = 0.f;
  int i = blockIdx.x * 256 + t;
  s[t] = (i < NN) ? deg[i] : 0;
  __syncthreads();
#pragma unroll
  for (int off = 128; off > 0; off >>= 1) {
    if (t < off) s[t] += s[t + off];
    __syncthreads();
  }
  if (t == 0) bsum[blockIdx.x] = s[0];
}

// -------- scanB: redundant block-prefix + local scan -> offs / cursor -------
__global__ __launch_bounds__(256) void scanB(const int* __restrict__ deg,
                                             const int* __restrict__ bsum,
                                             int* __restrict__ offs,
                                             int* __restrict__ cursor) {
  __shared__ int s[256];
  __shared__ int bpref;
  int t = threadIdx.x;
  int bid = blockIdx.x;
  int i = bid * 256 + t;
  int v = (i < NN) ? deg[i] : 0;
  s[t] = v;
  if (t == 0) {
    int r = 0;
    for (int k = 0; k < bid; ++k) r += bsum[k];
    bpref = r;
  }
  __syncthreads();
  for (int off = 1; off < 256; off <<= 1) {
    int u = (t >= off) ? s[t - off] : 0;
    __syncthreads();
    s[t] += u;
    __syncthreads();
  }
  int excl = s[t] - v + bpref;
  if (i <= NN) {
    offs[i] = excl;
    if (i < NN) cursor[i] = excl;
  }
}

__global__ void fill_csr(const int* __restrict__ ei, int* __restrict__ cursor,
                         int* __restrict__ csr) {
  int e = blockIdx.x * 256 + threadIdx.x;
  if (e >= ETOT) return;
  int s, d;
  if (e < EE) { s = ei[e]; d = ei[EE + e]; }
  else { s = e - EE; d = s; }
  int pos = atomicAdd(&cursor[d], 1);
  csr[pos] = s;
}

// ---------------- fused score + segment-softmax (max-free) + aggregation ----
// One node per 16-lane group (8 ch/lane), 4 nodes per wave; 8 uint4 row
// gathers in flight per group step; head reduce = 2 shfl_xor in 4-lane quads.
__global__ __launch_bounds__(256) void aggregate(
    const unsigned short* __restrict__ xlh, const float* __restrict__ xr,
    const int* __restrict__ offs, const int* __restrict__ csr,
    const float* __restrict__ att,
    float* __restrict__ out, float* __restrict__ bn) {
  __shared__ float sbn[256];
  int t = threadIdx.x;
  sbn[t] = 0.f;
  __syncthreads();
  const int lane = t & 63;
  const int gl = lane & 15;          // lane within group
  const int gb = lane & 48;          // group base lane
  const int c8 = gl * 8;
  const int gid = (blockIdx.x * 256 + t) >> 4;
  const int gstride = gridDim.x * 16;
  const float4 at0 = *(const float4*)&att[c8];
  const float4 at1 = *(const float4*)&att[c8 + 4];
  float4 bs0 = make_float4(0, 0, 0, 0), bs1 = make_float4(0, 0, 0, 0);
  float4 bq0 = make_float4(0, 0, 0, 0), bq1 = make_float4(0, 0, 0, 0);

  for (int node = gid; node < NN; node += gstride) {
    const float4 xr0 = *(const float4*)&xr[(size_t)node * 128 + c8];
    const float4 xr1 = *(const float4*)&xr[(size_t)node * 128 + c8 + 4];
    const int beg = offs[node];
    const int deg = offs[node + 1] - beg;
    float den = 0.f;
    float4 a0 = make_float4(0, 0, 0, 0), a1 = make_float4(0, 0, 0, 0);

    for (int base = 0; base < deg; base += 16) {
      int cnt = deg - base; if (cnt > 16) cnt = 16;
      int msrc = (gl < cnt) ? csr[beg + base + gl] : 0;
      for (int eb = 0; eb < cnt; eb += 8) {
        uint4 u[8];
#pragma unroll
        for (int j = 0; j < 8; ++j) {
          int s = __shfl(msrc, gb + eb + j, 64);
          u[j] = *(const uint4*)(xlh + (size_t)s * 128 + c8);
        }
#pragma unroll
        for (int j = 0; j < 8; ++j) {
          float4 v0 = unpack_bf16x4(u[j].x, u[j].y);
          float4 v1 = unpack_bf16x4(u[j].z, u[j].w);
          float e, p;
          e = v0.x + xr0.x; e = e > 0.f ? e : 0.2f * e; p = e * at0.x;
          e = v0.y + xr0.y; e = e > 0.f ? e : 0.2f * e; p = fmaf(e, at0.y, p);
          e = v0.z + xr0.z; e = e > 0.f ? e : 0.2f * e; p = fmaf(e, at0.z, p);
          e = v0.w + xr0.w; e = e > 0.f ? e : 0.2f * e; p = fmaf(e, at0.w, p);
          e = v1.x + xr1.x; e = e > 0.f ? e : 0.2f * e; p = fmaf(e, at1.x, p);
          e = v1.y + xr1.y; e = e > 0.f ? e : 0.2f * e; p = fmaf(e, at1.y, p);
          e = v1.z + xr1.z; e = e > 0.f ? e : 0.2f * e; p = fmaf(e, at1.z, p);
          e = v1.w + xr1.w; e = e > 0.f ? e : 0.2f * e; p = fmaf(e, at1.w, p);
          p += __shfl_xor(p, 1);
          p += __shfl_xor(p, 2);
          float pe = (eb + j < cnt) ? __expf(p) : 0.f;
          den += pe;
          a0.x = fmaf(pe, v0.x, a0.x);
          a0.y = fmaf(pe, v0.y, a0.y);
          a0.z = fmaf(pe, v0.z, a0.z);
          a0.w = fmaf(pe, v0.w, a0.w);
          a1.x = fmaf(pe, v1.x, a1.x);
          a1.y = fmaf(pe, v1.y, a1.y);
          a1.z = fmaf(pe, v1.z, a1.z);
          a1.w = fmaf(pe, v1.w, a1.w);
        }
      }
    }

    float inv = 1.0f / den;
    float4 r0, r1;
    r0.x = a0.x * inv; r0.y = a0.y * inv; r0.z = a0.z * inv; r0.w = a0.w * inv;
    r1.x = a1.x * inv; r1.y = a1.y * inv; r1.z = a1.z * inv; r1.w = a1.w * inv;
    *(float4*)&out[(size_t)node * 128 + c8] = r0;
    *(float4*)&out[(size_t)node * 128 + c8 + 4] = r1;
    bs0.x += r0.x; bs0.y += r0.y; bs0.z += r0.z; bs0.w += r0.w;
    bs1.x += r1.x; bs1.y += r1.y; bs1.z += r1.z; bs1.w += r1.w;
    bq0.x += r0.x * r0.x; bq0.y += r0.y * r0.y; bq0.z += r0.z * r0.z; bq0.w += r0.w * r0.w;
    bq1.x += r1.x * r1.x; bq1.y += r1.y * r1.y; bq1.z += r1.z * r1.z; bq1.w += r1.w * r1.w;
  }

#define RED(F) F = F + __shfl_xor(F, 16); F = F + __shfl_xor(F, 32);
  RED(bs0.x) RED(bs0.y) RED(bs0.z) RED(bs0.w)
  RED(bs1.x) RED(bs1.y) RED(bs1.z) RED(bs1.w)
  RED(bq0.x) RED(bq0.y) RED(bq0.z) RED(bq0.w)
  RED(bq1.x) RED(bq1.y) RED(bq1.z) RED(bq1.w)
#undef RED
  if (lane < 16) {
    atomicAdd(&sbn[c8 + 0], bs0.x);
    atomicAdd(&sbn[c8 + 1], bs0.y);
    atomicAdd(&sbn[c8 + 2], bs0.z);
    atomicAdd(&sbn[c8 + 3], bs0.w);
    atomicAdd(&sbn[c8 + 4], bs1.x);
    atomicAdd(&sbn[c8 + 5], bs1.y);
    atomicAdd(&sbn[c8 + 6], bs1.z);
    atomicAdd(&sbn[c8 + 7], bs1.w);
    atomicAdd(&sbn[128 + c8 + 0], bq0.x);
    atomicAdd(&sbn[128 + c8 + 1], bq0.y);
    atomicAdd(&sbn[128 + c8 + 2], bq0.z);
    atomicAdd(&sbn[128 + c8 + 3], bq0.w);
    atomicAdd(&sbn[128 + c8 + 4], bq1.x);
    atomicAdd(&sbn[128 + c8 + 5], bq1.y);
    atomicAdd(&sbn[128 + c8 + 6], bq1.z);
    atomicAdd(&sbn[128 + c8 + 7], bq1.w);
  }
  __syncthreads();
  atomicAdd(&bn[t], sbn[t]);
}

// ---------------- BN-normalize + residual + ELU (in place on d_out) ----------
__global__ __launch_bounds__(256) void finalize(
    float* __restrict__ out, const float* __restrict__ x,
    const float* __restrict__ bn, const float* __restrict__ gamma,
    const float* __restrict__ beta) {
  __shared__ float smu[128], sgi[128];
  int t = threadIdx.x;
  if (t < 128) {
    float mu = bn[t] * (1.0f / NN);
    float var = bn[128 + t] * (1.0f / NN) - mu * mu;
    smu[t] = mu;
    sgi[t] = rsqrtf(var + 1e-5f) * gamma[t];
  }
  __syncthreads();
  const int total4 = NN * 32;
  for (int i = blockIdx.x * blockDim.x + threadIdx.x; i < total4;
       i += gridDim.x * blockDim.x) {
    int c4 = (i & 31) * 4;
    float4 o = ((const float4*)out)[i];
    float4 xv = ((const float4*)x)[i];
    float4 mu = *(const float4*)&smu[c4];
    float4 gi = *(const float4*)&sgi[c4];
    float4 b4 = *(const float4*)&beta[c4];
    float v;
    v = (o.x - mu.x) * gi.x + b4.x + xv.x; o.x = v > 0.f ? v : expm1f(v);
    v = (o.y - mu.y) * gi.y + b4.y + xv.y; o.y = v > 0.f ? v : expm1f(v);
    v = (o.z - mu.z) * gi.z + b4.z + xv.z; o.z = v > 0.f ? v : expm1f(v);
    v = (o.w - mu.w) * gi.w + b4.w + xv.w; o.w = v > 0.f ? v : expm1f(v);
    ((float4*)out)[i] = o;
  }
}

extern "C" void kernel_launch(void* const* d_in, const int* in_sizes, int n_in,
                              void* d_out, int out_size, void* d_ws, size_t ws_size,
                              hipStream_t stream) {
  const float* x    = (const float*)d_in[0];
  const int*   ei   = (const int*)d_in[1];
  const float* Wl   = (const float*)d_in[2];
  const float* bl   = (const float*)d_in[3];
  const float* Wr   = (const float*)d_in[4];
  const float* br   = (const float*)d_in[5];
  const float* att  = (const float*)d_in[6];
  const float* gam  = (const float*)d_in[8];
  const float* bet  = (const float*)d_in[9];
  float* out = (float*)d_out;

  unsigned short* xlh = (unsigned short*)d_ws;        // NN*128 bf16
  float* xr   = (float*)(xlh + (size_t)NN * 128);     // NN*128 f32
  int* offs   = (int*)(xr + (size_t)NN * 128);        // NN+4 ints
  int* cursor = offs + (NN + 4);                      // NN ints
  int* deg    = cursor + NN;                          // NN ints
  int* csr    = deg + NN;                             // ETOT ints
  float* bn   = (float*)(csr + ETOT);                 // 256 f32: sum | sumsq
  int* bsum   = (int*)(bn + 256);                     // 256 ints

  hipMemsetD32Async((hipDeviceptr_t)deg, 1, NN, stream);  // self-loop

  hipLaunchKernelGGL(gemm_count, dim3(GEMM_GRID + COUNT_BLOCKS), dim3(256), 0,
                     stream, x, Wl, bl, Wr, br, xlh, xr, ei, deg);
  hipLaunchKernelGGL(scanA, dim3(SCAN_BLOCKS), dim3(256), 0, stream, deg, bsum, bn);
  hipLaunchKernelGGL(scanB, dim3(SCAN_BLOCKS), dim3(256), 0, stream,
                     deg, bsum, offs, cursor);
  hipLaunchKernelGGL(fill_csr, dim3((ETOT + 255) / 256), dim3(256), 0, stream,
                     ei, cursor, csr);
  hipLaunchKernelGGL(aggregate, dim3(AGG_BLOCKS), dim3(256), 0, stream,
                     xlh, xr, offs, csr, att, out, bn);
  hipLaunchKernelGGL(finalize, dim3(2048), dim3(256), 0, stream, out, x, bn, gam, bet);
}

// Round 8
// 282.087 us; speedup vs baseline: 1.7983x; 1.0593x over previous
//
#include <hip/hip_runtime.h>

#define NN 50000
#define EE 800000
#define ETOT (EE + NN)
#define GEMM_GRID 391      // x2 M-tiles each = 782
#define MTILES 782         // ceil(NN/64)
#define COUNT_BLOCKS 3125  // EE/256 exactly
#define AGG_BLOCKS 1024
#define SCAN_BLOCKS 196    // ceil(NN/256)

typedef __attribute__((ext_vector_type(8))) short bhalf8;  // 8 bf16 (4 VGPR)
typedef __attribute__((ext_vector_type(4))) float fx4;     // mfma acc

__device__ __forceinline__ unsigned bf16r(float f) {  // RNE float->bf16 bits
  unsigned u = __float_as_uint(f);
  return (u + 0x7FFFu + ((u >> 16) & 1u)) >> 16;
}

__device__ __forceinline__ float4 unpack_bf16x4(unsigned a, unsigned b) {
  float4 f;
  f.x = __uint_as_float(a << 16);
  f.y = __uint_as_float(a & 0xFFFF0000u);
  f.z = __uint_as_float(b << 16);
  f.w = __uint_as_float(b & 0xFFFF0000u);
  return f;
}

// ---- fused: MFMA GEMM (blocks 0..390) | degree count (blocks 391..3515) ----
// GEMM: [50000x128] @ [128x(128|128)] -> xlh (bf16), xr (f32), bias folded in.
// W staged coalesced into LDS as bf16 [col][k] (pitch 136 -> 2-way bank alias,
// free), then 16 ds_read_b128 per wave -> register-resident fragments.
// A-frag: row=lane&15, k=(lane>>4)*8+j ; B-frag: col=lane&15, same k.
// C/D: col=lane&15, row=(lane>>4)*4+reg  [layout validated by R6 pass]
__global__ __launch_bounds__(256) void gemm_count(
    const float* __restrict__ x,
    const float* __restrict__ Wl, const float* __restrict__ bl,
    const float* __restrict__ Wr, const float* __restrict__ br,
    unsigned short* __restrict__ xlh, float* __restrict__ xr,
    const int* __restrict__ ei, int* __restrict__ deg) {
  if (blockIdx.x >= GEMM_GRID) {
    int e = (blockIdx.x - GEMM_GRID) * 256 + threadIdx.x;
    if (e < EE) atomicAdd(&deg[ei[EE + e]], 1);
    return;
  }
  __shared__ unsigned short sW[256 * 136];
  const int t = threadIdx.x;
  const int w = t >> 6;        // wave 0..3
  const int l = t & 63;
  const int cl = l & 15;       // row (A) / col (B,D) within 16
  const int kb = (l >> 4) * 8; // k sub-offset within 32-chunk
  const int rsub = (l >> 4) * 4;

  // ---- stage W (both halves) into LDS, coalesced ----
#pragma unroll
  for (int it = 0; it < 16; ++it) {
    int f4 = t + it * 256;          // 0..4095
    int k = f4 >> 5;                // 0..127
    int c4 = (f4 & 31) * 4;         // 0..124
    float4 v = *(const float4*)&Wl[(size_t)k * 128 + c4];
    sW[(c4 + 0) * 136 + k] = (unsigned short)bf16r(v.x);
    sW[(c4 + 1) * 136 + k] = (unsigned short)bf16r(v.y);
    sW[(c4 + 2) * 136 + k] = (unsigned short)bf16r(v.z);
    sW[(c4 + 3) * 136 + k] = (unsigned short)bf16r(v.w);
    float4 u = *(const float4*)&Wr[(size_t)k * 128 + c4];
    sW[(128 + c4 + 0) * 136 + k] = (unsigned short)bf16r(u.x);
    sW[(128 + c4 + 1) * 136 + k] = (unsigned short)bf16r(u.y);
    sW[(128 + c4 + 2) * 136 + k] = (unsigned short)bf16r(u.z);
    sW[(128 + c4 + 3) * 136 + k] = (unsigned short)bf16r(u.w);
  }
  __syncthreads();

  // ---- fragments + bias (registers, one-time) ----
  bhalf8 bfr[4][4];  // [nt][ch]
  float biasv[4];
#pragma unroll
  for (int nt = 0; nt < 4; ++nt) {
    int col = w * 64 + nt * 16 + cl;  // wave-uniform side of the 128-split
    biasv[nt] = (col < 128) ? bl[col] : br[col - 128];
#pragma unroll
    for (int ch = 0; ch < 4; ++ch)
      bfr[nt][ch] = *(const bhalf8*)&sW[col * 136 + ch * 32 + kb];
  }

  // ---- persistent M-tile loop (64 rows per tile, 2 tiles per block) ----
  for (int mt = blockIdx.x; mt < MTILES; mt += GEMM_GRID) {
    const int m0 = mt * 64;
#pragma unroll
    for (int rt = 0; rt < 4; ++rt) {
      int row = m0 + rt * 16 + cl;
      int rowc = row < NN ? row : NN - 1;
      const float* xp = x + (size_t)rowc * 128 + kb;
      bhalf8 afr[4];
#pragma unroll
      for (int ch = 0; ch < 4; ++ch) {
        float4 q0 = *(const float4*)(xp + ch * 32);
        float4 q1 = *(const float4*)(xp + ch * 32 + 4);
        bhalf8 f;
        f[0] = (short)bf16r(q0.x); f[1] = (short)bf16r(q0.y);
        f[2] = (short)bf16r(q0.z); f[3] = (short)bf16r(q0.w);
        f[4] = (short)bf16r(q1.x); f[5] = (short)bf16r(q1.y);
        f[6] = (short)bf16r(q1.z); f[7] = (short)bf16r(q1.w);
        afr[ch] = f;
      }
#pragma unroll
      for (int nt = 0; nt < 4; ++nt) {
        fx4 acc = {biasv[nt], biasv[nt], biasv[nt], biasv[nt]};
#pragma unroll
        for (int ch = 0; ch < 4; ++ch)
          acc = __builtin_amdgcn_mfma_f32_16x16x32_bf16(afr[ch], bfr[nt][ch],
                                                        acc, 0, 0, 0);
        int col = w * 64 + nt * 16 + cl;
        int rbase = m0 + rt * 16 + rsub;
        if (col < 128) {  // wave-uniform branch
#pragma unroll
          for (int r = 0; r < 4; ++r) {
            int rr = rbase + r;
            if (rr < NN) xlh[(size_t)rr * 128 + col] = (unsigned short)bf16r(acc[r]);
          }
        } else {
          int c2 = col - 128;
#pragma unroll
          for (int r = 0; r < 4; ++r) {
            int rr = rbase + r;
            if (rr < NN) xr[(size_t)rr * 128 + c2] = acc[r];
          }
        }
      }
    }
  }
}

// ---------------- scanA: per-block reduce of deg; zero bn ----------------
__global__ __launch_bounds__(256) void scanA(const int* __restrict__ deg,
                                             int* __restrict__ bsum,
                                             float* __restrict__ bn) {
  __shared__ int s[256];
  int t = threadIdx.x;
  if (blockIdx.x == 0) bn[t] = 0.f;
  int i = blockIdx.x * 256 + t;
  s[t] = (i < NN) ? deg[i] : 0;
  __syncthreads();
#pragma unroll
  for (int off = 128; off > 0; off >>= 1) {
    if (t < off) s[t] += s[t + off];
    __syncthreads();
  }
  if (t == 0) bsum[blockIdx.x] = s[0];
}

// -------- scanB: redundant block-prefix + local scan -> offs / cursor -------
__global__ __launch_bounds__(256) void scanB(const int* __restrict__ deg,
                                             const int* __restrict__ bsum,
                                             int* __restrict__ offs,
                                             int* __restrict__ cursor) {
  __shared__ int s[256];
  __shared__ int bpref;
  int t = threadIdx.x;
  int bid = blockIdx.x;
  int i = bid * 256 + t;
  int v = (i < NN) ? deg[i] : 0;
  s[t] = v;
  if (t == 0) {
    int r = 0;
    for (int k = 0; k < bid; ++k) r += bsum[k];
    bpref = r;
  }
  __syncthreads();
  for (int off = 1; off < 256; off <<= 1) {
    int u = (t >= off) ? s[t - off] : 0;
    __syncthreads();
    s[t] += u;
    __syncthreads();
  }
  int excl = s[t] - v + bpref;
  if (i <= NN) {
    offs[i] = excl;
    if (i < NN) cursor[i] = excl;
  }
}

__global__ void fill_csr(const int* __restrict__ ei, int* __restrict__ cursor,
                         int* __restrict__ csr) {
  int e = blockIdx.x * 256 + threadIdx.x;
  if (e >= ETOT) return;
  int s, d;
  if (e < EE) { s = ei[e]; d = ei[EE + e]; }
  else { s = e - EE; d = s; }
  int pos = atomicAdd(&cursor[d], 1);
  csr[pos] = s;
}

// ---------------- fused score + segment-softmax (max-free) + aggregation ----
// One node per 16-lane group (8 ch/lane). Per 32-edge super-chunk: two
// coalesced csr reads, then 8-edge sub-batches with DOUBLE-BUFFERED row
// gathers (issue batch b+1 before consuming batch b -> latency hidden under
// ~100 VALU insts of consume). Buffers indexed by compile-time constants only.
__global__ __launch_bounds__(256) void aggregate(
    const unsigned short* __restrict__ xlh, const float* __restrict__ xr,
    const int* __restrict__ offs, const int* __restrict__ csr,
    const float* __restrict__ att,
    float* __restrict__ out, float* __restrict__ bn) {
  __shared__ float sbn[256];
  int t = threadIdx.x;
  sbn[t] = 0.f;
  __syncthreads();
  const int lane = t & 63;
  const int gl = lane & 15;          // lane within group
  const int gb = lane & 48;          // group base lane
  const int c8 = gl * 8;
  const int gid = (blockIdx.x * 256 + t) >> 4;
  const int gstride = gridDim.x * 16;
  const float4 at0 = *(const float4*)&att[c8];
  const float4 at1 = *(const float4*)&att[c8 + 4];
  float4 bs0 = make_float4(0, 0, 0, 0), bs1 = make_float4(0, 0, 0, 0);
  float4 bq0 = make_float4(0, 0, 0, 0), bq1 = make_float4(0, 0, 0, 0);

#define LOADB(buf, bb) do {                                                   \
    int mm = ((bb) >= 2) ? m1 : m0;                                           \
    int ebase = gb + (((bb) & 1) << 3);                                       \
    _Pragma("unroll")                                                         \
    for (int j = 0; j < 8; ++j) {                                             \
      int s = __shfl(mm, ebase + j, 64);                                      \
      buf[j] = *(const uint4*)(xlh + (size_t)s * 128 + c8);                   \
    }                                                                         \
  } while (0)

#define CONSUME(buf, bb) do {                                                 \
    _Pragma("unroll")                                                         \
    for (int j = 0; j < 8; ++j) {                                             \
      float4 v0 = unpack_bf16x4(buf[j].x, buf[j].y);                          \
      float4 v1 = unpack_bf16x4(buf[j].z, buf[j].w);                          \
      float e, p;                                                             \
      e = v0.x + xr0.x; e = e > 0.f ? e : 0.2f * e; p = e * at0.x;            \
      e = v0.y + xr0.y; e = e > 0.f ? e : 0.2f * e; p = fmaf(e, at0.y, p);    \
      e = v0.z + xr0.z; e = e > 0.f ? e : 0.2f * e; p = fmaf(e, at0.z, p);    \
      e = v0.w + xr0.w; e = e > 0.f ? e : 0.2f * e; p = fmaf(e, at0.w, p);    \
      e = v1.x + xr1.x; e = e > 0.f ? e : 0.2f * e; p = fmaf(e, at1.x, p);    \
      e = v1.y + xr1.y; e = e > 0.f ? e : 0.2f * e; p = fmaf(e, at1.y, p);    \
      e = v1.z + xr1.z; e = e > 0.f ? e : 0.2f * e; p = fmaf(e, at1.z, p);    \
      e = v1.w + xr1.w; e = e > 0.f ? e : 0.2f * e; p = fmaf(e, at1.w, p);    \
      p += __shfl_xor(p, 1);                                                  \
      p += __shfl_xor(p, 2);                                                  \
      float pe = ((bb) * 8 + j < rem) ? __expf(p) : 0.f;                      \
      den += pe;                                                              \
      a0.x = fmaf(pe, v0.x, a0.x);                                            \
      a0.y = fmaf(pe, v0.y, a0.y);                                            \
      a0.z = fmaf(pe, v0.z, a0.z);                                            \
      a0.w = fmaf(pe, v0.w, a0.w);                                            \
      a1.x = fmaf(pe, v1.x, a1.x);                                            \
      a1.y = fmaf(pe, v1.y, a1.y);                                            \
      a1.z = fmaf(pe, v1.z, a1.z);                                            \
      a1.w = fmaf(pe, v1.w, a1.w);                                            \
    }                                                                         \
  } while (0)

  for (int node = gid; node < NN; node += gstride) {
    const float4 xr0 = *(const float4*)&xr[(size_t)node * 128 + c8];
    const float4 xr1 = *(const float4*)&xr[(size_t)node * 128 + c8 + 4];
    const int beg = offs[node];
    const int deg = offs[node + 1] - beg;
    float den = 0.f;
    float4 a0 = make_float4(0, 0, 0, 0), a1 = make_float4(0, 0, 0, 0);

    for (int base = 0; base < deg; base += 32) {
      int rem = deg - base; if (rem > 32) rem = 32;
      int m0 = (gl < rem)      ? csr[beg + base + gl]      : 0;
      int m1 = (16 + gl < rem) ? csr[beg + base + 16 + gl] : 0;
      int nb = (rem + 7) >> 3;
      uint4 bufA[8], bufB[8];
      LOADB(bufA, 0);
      int b = 0;
      for (;;) {
        if (b + 1 < nb) LOADB(bufB, b + 1);
        CONSUME(bufA, b);
        if (++b >= nb) break;
        if (b + 1 < nb) LOADB(bufA, b + 1);
        CONSUME(bufB, b);
        if (++b >= nb) break;
      }
    }

    float inv = 1.0f / den;
    float4 r0, r1;
    r0.x = a0.x * inv; r0.y = a0.y * inv; r0.z = a0.z * inv; r0.w = a0.w * inv;
    r1.x = a1.x * inv; r1.y = a1.y * inv; r1.z = a1.z * inv; r1.w = a1.w * inv;
    *(float4*)&out[(size_t)node * 128 + c8] = r0;
    *(float4*)&out[(size_t)node * 128 + c8 + 4] = r1;
    bs0.x += r0.x; bs0.y += r0.y; bs0.z += r0.z; bs0.w += r0.w;
    bs1.x += r1.x; bs1.y += r1.y; bs1.z += r1.z; bs1.w += r1.w;
    bq0.x += r0.x * r0.x; bq0.y += r0.y * r0.y; bq0.z += r0.z * r0.z; bq0.w += r0.w * r0.w;
    bq1.x += r1.x * r1.x; bq1.y += r1.y * r1.y; bq1.z += r1.z * r1.z; bq1.w += r1.w * r1.w;
  }
#undef LOADB
#undef CONSUME

#define RED(F) F = F + __shfl_xor(F, 16); F = F + __shfl_xor(F, 32);
  RED(bs0.x) RED(bs0.y) RED(bs0.z) RED(bs0.w)
  RED(bs1.x) RED(bs1.y) RED(bs1.z) RED(bs1.w)
  RED(bq0.x) RED(bq0.y) RED(bq0.z) RED(bq0.w)
  RED(bq1.x) RED(bq1.y) RED(bq1.z) RED(bq1.w)
#undef RED
  if (lane < 16) {
    atomicAdd(&sbn[c8 + 0], bs0.x);
    atomicAdd(&sbn[c8 + 1], bs0.y);
    atomicAdd(&sbn[c8 + 2], bs0.z);
    atomicAdd(&sbn[c8 + 3], bs0.w);
    atomicAdd(&sbn[c8 + 4], bs1.x);
    atomicAdd(&sbn[c8 + 5], bs1.y);
    atomicAdd(&sbn[c8 + 6], bs1.z);
    atomicAdd(&sbn[c8 + 7], bs1.w);
    atomicAdd(&sbn[128 + c8 + 0], bq0.x);
    atomicAdd(&sbn[128 + c8 + 1], bq0.y);
    atomicAdd(&sbn[128 + c8 + 2], bq0.z);
    atomicAdd(&sbn[128 + c8 + 3], bq0.w);
    atomicAdd(&sbn[128 + c8 + 4], bq1.x);
    atomicAdd(&sbn[128 + c8 + 5], bq1.y);
    atomicAdd(&sbn[128 + c8 + 6], bq1.z);
    atomicAdd(&sbn[128 + c8 + 7], bq1.w);
  }
  __syncthreads();
  atomicAdd(&bn[t], sbn[t]);
}

// ---------------- BN-normalize + residual + ELU (in place on d_out) ----------
__global__ __launch_bounds__(256) void finalize(
    float* __restrict__ out, const float* __restrict__ x,
    const float* __restrict__ bn, const float* __restrict__ gamma,
    const float* __restrict__ beta) {
  __shared__ float smu[128], sgi[128];
  int t = threadIdx.x;
  if (t < 128) {
    float mu = bn[t] * (1.0f / NN);
    float var = bn[128 + t] * (1.0f / NN) - mu * mu;
    smu[t] = mu;
    sgi[t] = rsqrtf(var + 1e-5f) * gamma[t];
  }
  __syncthreads();
  const int total4 = NN * 32;
  for (int i = blockIdx.x * blockDim.x + threadIdx.x; i < total4;
       i += gridDim.x * blockDim.x) {
    int c4 = (i & 31) * 4;
    float4 o = ((const float4*)out)[i];
    float4 xv = ((const float4*)x)[i];
    float4 mu = *(const float4*)&smu[c4];
    float4 gi = *(const float4*)&sgi[c4];
    float4 b4 = *(const float4*)&beta[c4];
    float v;
    v = (o.x - mu.x) * gi.x + b4.x + xv.x; o.x = v > 0.f ? v : expm1f(v);
    v = (o.y - mu.y) * gi.y + b4.y + xv.y; o.y = v > 0.f ? v : expm1f(v);
    v = (o.z - mu.z) * gi.z + b4.z + xv.z; o.z = v > 0.f ? v : expm1f(v);
    v = (o.w - mu.w) * gi.w + b4.w + xv.w; o.w = v > 0.f ? v : expm1f(v);
    ((float4*)out)[i] = o;
  }
}

extern "C" void kernel_launch(void* const* d_in, const int* in_sizes, int n_in,
                              void* d_out, int out_size, void* d_ws, size_t ws_size,
                              hipStream_t stream) {
  const float* x    = (const float*)d_in[0];
  const int*   ei   = (const int*)d_in[1];
  const float* Wl   = (const float*)d_in[2];
  const float* bl   = (const float*)d_in[3];
  const float* Wr   = (const float*)d_in[4];
  const float* br   = (const float*)d_in[5];
  const float* att  = (const float*)d_in[6];
  const float* gam  = (const float*)d_in[8];
  const float* bet  = (const float*)d_in[9];
  float* out = (float*)d_out;

  unsigned short* xlh = (unsigned short*)d_ws;        // NN*128 bf16
  float* xr   = (float*)(xlh + (size_t)NN * 128);     // NN*128 f32
  int* offs   = (int*)(xr + (size_t)NN * 128);        // NN+4 ints
  int* cursor = offs + (NN + 4);                      // NN ints
  int* deg    = cursor + NN;                          // NN ints
  int* csr    = deg + NN;                             // ETOT ints
  float* bn   = (float*)(csr + ETOT);                 // 256 f32: sum | sumsq
  int* bsum   = (int*)(bn + 256);                     // 256 ints

  hipMemsetD32Async((hipDeviceptr_t)deg, 1, NN, stream);  // self-loop

  hipLaunchKernelGGL(gemm_count, dim3(GEMM_GRID + COUNT_BLOCKS), dim3(256), 0,
                     stream, x, Wl, bl, Wr, br, xlh, xr, ei, deg);
  hipLaunchKernelGGL(scanA, dim3(SCAN_BLOCKS), dim3(256), 0, stream, deg, bsum, bn);
  hipLaunchKernelGGL(scanB, dim3(SCAN_BLOCKS), dim3(256), 0, stream,
                     deg, bsum, offs, cursor);
  hipLaunchKernelGGL(fill_csr, dim3((ETOT + 255) / 256), dim3(256), 0, stream,
                     ei, cursor, csr);
  hipLaunchKernelGGL(aggregate, dim3(AGG_BLOCKS), dim3(256), 0, stream,
                     xlh, xr, offs, csr, att, out, bn);
  hipLaunchKernelGGL(finalize, dim3(2048), dim3(256), 0, stream, out, x, bn, gam, bet);
}